// Round 11
// baseline (501.344 us; speedup 1.0000x reference)
//
#include <hip/hip_runtime.h>
#include <math.h>

#define NN 20000
#define NE 320000
#define TS 16
#define HG 64
#define HTT 128
#define NG 384   // 3*HT
#define LN_EPS 1e-5f

typedef __attribute__((ext_vector_type(8))) _Float16 f16x8;
typedef __attribute__((ext_vector_type(4))) _Float16 f16x4;
typedef __attribute__((ext_vector_type(2))) _Float16 f16x2;
typedef __attribute__((ext_vector_type(4))) float f32x4;

__device__ __forceinline__ float wave_sum64(float v) {
  #pragma unroll
  for (int off = 32; off > 0; off >>= 1) v += __shfl_xor(v, off, 64);
  return v;
}
__device__ __forceinline__ float quad_sum16(float v) {
  #pragma unroll
  for (int off = 1; off < 16; off <<= 1) v += __shfl_xor(v, off, 64);
  return v;
}
__device__ __forceinline__ float fast_sigmoid(float x) {
  return __builtin_amdgcn_rcpf(1.f + __expf(-x));
}
__device__ __forceinline__ float fast_tanh(float x) {
  float e = __expf(-2.f * fabsf(x));
  float th = (1.f - e) * __builtin_amdgcn_rcpf(1.f + e);
  return copysignf(th, x);
}

// ============================================================================
// Journal of refuted branches (do not retry without per-kernel evidence):
//  - gru (256,4) on 4-wave form: VGPR forced 64 -> full spill -> 375 us (R5).
//  - gru Wih from global instead of LDS: +45 us (R6).
//  - gru gah prefetch: neutral (R7).
//  - h0r elimination (reconstruct in k_gemm): +31 us (R8/R9/R10 A/B).
//  - k_gather 2-deep ping-pong: +20 us (R7 vs R4, confirmed by R10 revert).
//  - hist fused into setup + memsetAsync: neutral (R8 vs R9 A/B).
// R11: k_gru_all re-tiled 32n/4w -> 64n/8w (one gate-tile per wave).
//  Grid 625->313 <= 512-slot capacity: removes the 2nd dispatch round.
//  wgh 96->48 VGPR; hL single-buffered (2 barriers/t); LDS 66->64.5 KB.
// ============================================================================

// ---------------- fused setup: cnt-zero + weight cvts + moments + x transpose ----------------
__global__ __launch_bounds__(256) void k_setup(
    const float* __restrict__ x_seq, float* __restrict__ xT,
    const float* __restrict__ Wih, _Float16* __restrict__ WihF,
    const float* __restrict__ Whh, _Float16* __restrict__ WhhF,
    const float* __restrict__ Wl1, const float* __restrict__ Wr1,
    _Float16* __restrict__ Wchi, _Float16* __restrict__ Wclo,
    const float* __restrict__ Wl0, const float* __restrict__ Wr0,
    const float* __restrict__ b0, const float* __restrict__ g0,
    const float* __restrict__ be0, float* __restrict__ P,
    int* __restrict__ cnt) {
  int gid = blockIdx.x * 256 + threadIdx.x;
  int stride = gridDim.x * 256;
  for (int i = gid; i < NN * TS; i += stride) {
    int t = i / NN, n = i - t * NN;
    xT[n * 16 + t] = x_seq[i];
  }
  for (int i = gid; i < NG * HG; i += stride) WihF[i] = (_Float16)Wih[i];
  for (int i = gid; i < NG * HTT; i += stride) WhhF[i] = (_Float16)Whh[i];
  for (int i = gid; i < HG * 128; i += stride) {
    int n = i >> 7, k = i & 127;
    float x = (k < HG) ? Wl1[k * HG + n] : Wr1[(k - HG) * HG + n];
    _Float16 h = (_Float16)x;
    Wchi[i] = h;
    Wclo[i] = (_Float16)(x - (float)h);
  }
  for (int i = gid; i < NN; i += stride) cnt[i] = 0;
  if (blockIdx.x == 0 && threadIdx.x < 64) {
    int f = threadIdx.x;
    float u = Wl0[f], v = Wr0[f], c = b0[f], g = g0[f];
    float um = wave_sum64(u) * (1.f / 64.f);
    float vm = wave_sum64(v) * (1.f / 64.f);
    float cm = wave_sum64(c) * (1.f / 64.f);
    float uc = u - um, vc = v - vm, cc = c - cm;
    float muu = wave_sum64(uc * uc) * (1.f / 64.f);
    float mvv = wave_sum64(vc * vc) * (1.f / 64.f);
    float mcc = wave_sum64(cc * cc) * (1.f / 64.f);
    float muv = wave_sum64(uc * vc) * (1.f / 64.f);
    float muc = wave_sum64(uc * cc) * (1.f / 64.f);
    float mvc = wave_sum64(vc * cc) * (1.f / 64.f);
    P[f] = uc * g; P[64 + f] = vc * g; P[128 + f] = cc * g; P[192 + f] = be0[f];
    if (f == 0) {
      P[256] = muu; P[257] = mvv; P[258] = mcc;
      P[259] = muv; P[260] = muc; P[261] = mvc;
    }
  }
}

__global__ void k_hist(const int* __restrict__ dst, int* cnt) {
  int e = blockIdx.x * blockDim.x + threadIdx.x;
  if (e < NE) atomicAdd(&cnt[dst[e]], 1);
}

// 1-pass scan: thread handles 20 elements in registers
__global__ void k_scan(int* cnt, int* row_ptr, float* deg_inv) {
  __shared__ int s[1024];
  const int PER = 20;
  int tid = threadIdx.x;
  int base = tid * PER;
  int vloc[PER], dloc[PER];
  int sum = 0;
  #pragma unroll
  for (int j = 0; j < PER; j++) {
    int n = base + j;
    int d = (n < NN) ? cnt[n] : 0;
    vloc[j] = sum;
    dloc[j] = d;
    sum += d;
  }
  s[tid] = sum;
  __syncthreads();
  for (int off = 1; off < 1024; off <<= 1) {
    int t = (tid >= off) ? s[tid - off] : 0;
    __syncthreads();
    s[tid] += t;
    __syncthreads();
  }
  int excl = s[tid] - sum;
  #pragma unroll
  for (int j = 0; j < PER; j++) {
    int n = base + j;
    if (n < NN) {
      int rp = excl + vloc[j];
      row_ptr[n] = rp;
      cnt[n] = rp;
      int d = dloc[j];
      deg_inv[n] = 1.0f / (float)((d > 1) ? d : 1);
    }
  }
  if (tid == 1023) row_ptr[NN] = s[1023];
}

__global__ void k_fill(const int* __restrict__ src, const int* __restrict__ dst,
                       int* cursor, int* col) {
  int e = blockIdx.x * blockDim.x + threadIdx.x;
  if (e < NE) {
    int p = atomicAdd(&cursor[dst[e]], 1);
    col[p] = src[e];
  }
}

// ---------------- fused agg0 + h0: wave per node ----------------
// Emits per-(n,t) LN code, PRE-DUPLICATED for pk-fp16 consumption:
// code2[n][t&7][t>>3] = [A,A,X,X,C,C,0,0] (16 B), where (A,X,C) =
// (a*rstd, x*rstd, rstd); h0[n][t][f] == max(A*P[f]+X*P[64+f]+C*P[128+f]+P[192+f],0).
// 5.12 MB total -> L2-resident on every XCD. k_gather gathers THIS instead
// of the 2 KB h0 rows; h0r stays materialized for k_gemm's root rows.
__global__ __launch_bounds__(256) void k_h0_fused(
    const float* __restrict__ xT,
    const int* __restrict__ row_ptr, const int* __restrict__ col,
    const float* __restrict__ deg_inv,
    const float* __restrict__ P,
    _Float16* __restrict__ h0r,      // [n][16][64]
    _Float16* __restrict__ code2) {  // [n][8][2][8]
  int lane = threadIdx.x & 63;
  int n = blockIdx.x * 4 + (threadIdx.x >> 6);
  int grp = lane >> 4, tl = lane & 15;
  int beg = row_ptr[n];
  int deg = row_ptr[n + 1] - beg;
  float s0 = 0.f, s1 = 0.f;
  int iters = (deg + 7) >> 3;
  for (int it = 0; it < iters; it++) {
    int e0 = it * 8 + grp, e1 = it * 8 + 4 + grp;
    bool v0 = e0 < deg, v1 = e1 < deg;
    int i0 = v0 ? e0 : 0, i1 = v1 ? e1 : 0;
    int c0 = col[beg + i0];
    int c1 = col[beg + i1];
    float x0 = xT[c0 * 16 + tl];
    float x1 = xT[c1 * 16 + tl];
    s0 += v0 ? x0 : 0.f;
    s1 += v1 ? x1 : 0.f;
  }
  float s = s0 + s1;
  s += __shfl_xor(s, 16, 64);
  s += __shfl_xor(s, 32, 64);
  float aggv = s * deg_inv[n];          // lane holds agg for t = lane&15
  float xv = xT[n * 16 + tl];           // lane holds x for t = lane&15
  float muu = P[256], mvv = P[257], mcc = P[258];
  float muv = P[259], muc = P[260], mvc = P[261];
  // emit duplicated LN code for t = lane (lanes 0..15)
  if (lane < 16) {
    float a = aggv, x = xv;
    float var = a * a * muu + x * x * mvv + mcc
              + 2.f * (a * x * muv + a * muc + x * mvc);
    float rstd = rsqrtf(var + LN_EPS);
    _Float16 Ah = (_Float16)(a * rstd);
    _Float16 Xh = (_Float16)(x * rstd);
    _Float16 Ch = (_Float16)rstd;
    f16x8 cw = {Ah, Ah, Xh, Xh, Ch, Ch, (_Float16)0.f, (_Float16)0.f};
    *(f16x8*)&code2[(size_t)n * 128 + (lane & 7) * 16 + (lane >> 3) * 8] = cw;
  }
  #pragma unroll
  for (int half = 0; half < 2; half++) {
    int c = lane + half * 64;           // chunk index 0..127
    int t = c >> 3, f8 = (c & 7) * 8;
    float a = __shfl(aggv, t, 64);
    float x = __shfl(xv, t, 64);
    float var = a * a * muu + x * x * mvv + mcc
              + 2.f * (a * x * muv + a * muc + x * mvc);
    float rstd = rsqrtf(var + LN_EPS);
    f16x8 o;
    #pragma unroll
    for (int j = 0; j < 8; j++) {
      int f = f8 + j;
      float d = a * P[f] + x * P[64 + f] + P[128 + f];
      o[j] = (_Float16)fmaxf(d * rstd + P[192 + f], 0.f);
    }
    *(f16x8*)&h0r[(size_t)n * 1024 + c * 8] = o;
  }
}

// ---------------- gather/reconstruct: wave per node, no LDS ----------------
// R4 form (simple 4-edge blocks; ping-pong variant refuted +20 us).
__global__ __launch_bounds__(256) void k_gather(
    const int* __restrict__ row_ptr, const int* __restrict__ col,
    const _Float16* __restrict__ code2,  // [n][8][2][8]
    const float* __restrict__ P,
    _Float16* __restrict__ agg) {        // [n][16][64]
  int lane = threadIdx.x & 63;
  int n = blockIdx.x * 4 + (threadIdx.x >> 6);
  const f16x2 h2z = {(_Float16)0.f, (_Float16)0.f};
  const f16x2 h2o = {(_Float16)1.f, (_Float16)1.f};
  // lane covers f = f1..f1+7 at t1 = lane>>3 and t2 = 8 + (lane>>3)
  int f1 = (lane & 7) * 8;
  int tmod = lane >> 3;
  f16x2 Pu2[4], Pv2[4], Pc2[4], Pb2[4];
  #pragma unroll
  for (int j = 0; j < 4; j++) {
    Pu2[j] = (f16x2){(_Float16)P[f1 + 2*j],       (_Float16)P[f1 + 2*j + 1]};
    Pv2[j] = (f16x2){(_Float16)P[64 + f1 + 2*j],  (_Float16)P[64 + f1 + 2*j + 1]};
    Pc2[j] = (f16x2){(_Float16)P[128 + f1 + 2*j], (_Float16)P[128 + f1 + 2*j + 1]};
    Pb2[j] = (f16x2){(_Float16)P[192 + f1 + 2*j], (_Float16)P[192 + f1 + 2*j + 1]};
  }
  int beg = row_ptr[n];
  int deg = row_ptr[n + 1] - beg;
  int cvAll = (lane < deg) ? col[beg + lane] : 0;

  f16x2 aE1[4], aO1[4], aE2[4], aO2[4];
  #pragma unroll
  for (int j = 0; j < 4; j++) { aE1[j] = h2z; aO1[j] = h2z; aE2[j] = h2z; aO2[j] = h2z; }

// accumulate one duplicated code (f16x8 [A,A,X,X,C,C,_,_]) into ACC[0..3]
#define ACC_SET(c, mk, FULL, ACC)                                          \
  { f16x2 _A = __builtin_shufflevector(c, c, 0, 1);                        \
    f16x2 _X = __builtin_shufflevector(c, c, 2, 3);                        \
    f16x2 _C = __builtin_shufflevector(c, c, 4, 5);                        \
    _Pragma("unroll")                                                      \
    for (int j = 0; j < 4; j++) {                                          \
      f16x2 d = __builtin_elementwise_fma(_A, Pu2[j],                      \
                 __builtin_elementwise_fma(_X, Pv2[j],                     \
                  __builtin_elementwise_fma(_C, Pc2[j], Pb2[j])));         \
      d = __builtin_elementwise_max(d, h2z);                               \
      ACC[j] = (FULL) ? (ACC[j] + d)                                       \
                      : __builtin_elementwise_fma(d, mk, ACC[j]);          \
    } }

  int nb4 = (deg + 3) >> 2;
  if (nb4 > 16) nb4 = 16;
  for (int b = 0; b < nb4; b++) {
    int eb = b << 2;
    f16x8 cA[4], cB[4];
    #pragma unroll
    for (int e = 0; e < 4; e++) {
      int c = __builtin_amdgcn_readlane(cvAll, eb + e);
      const _Float16* cp = code2 + (size_t)c * 128 + tmod * 16;
      cA[e] = *(const f16x8*)cp;
      cB[e] = *(const f16x8*)(cp + 8);
    }
    if (eb + 4 <= deg) {
      #pragma unroll
      for (int e = 0; e < 4; e++) {
        if (e & 1) { ACC_SET(cA[e], h2o, true, aO1) ACC_SET(cB[e], h2o, true, aO2) }
        else       { ACC_SET(cA[e], h2o, true, aE1) ACC_SET(cB[e], h2o, true, aE2) }
      }
    } else {
      #pragma unroll
      for (int e = 0; e < 4; e++) {
        f16x2 mk = ((eb + e) < deg) ? h2o : h2z;
        if (e & 1) { ACC_SET(cA[e], mk, false, aO1) ACC_SET(cB[e], mk, false, aO2) }
        else       { ACC_SET(cA[e], mk, false, aE1) ACC_SET(cB[e], mk, false, aE2) }
      }
    }
  }
  for (int e = 64; e < deg; e++) {        // rare tail (deg > 64)
    int c = col[beg + e];
    const _Float16* cp = code2 + (size_t)c * 128 + tmod * 16;
    f16x8 ca = *(const f16x8*)cp;
    f16x8 cb = *(const f16x8*)(cp + 8);
    ACC_SET(ca, h2o, true, aE1) ACC_SET(cb, h2o, true, aE2)
  }
#undef ACC_SET

  float dif = 1.0f / (float)((deg > 1) ? deg : 1);
  _Float16 dih = (_Float16)dif;
  f16x2 di2 = {dih, dih};
  union { f16x8 v; f16x2 h[4]; } u0, u1;
  #pragma unroll
  for (int j = 0; j < 4; j++) {
    u0.h[j] = (aE1[j] + aO1[j]) * di2;
    u1.h[j] = (aE2[j] + aO2[j]) * di2;
  }
  *(f16x8*)&agg[(size_t)n * 1024 + lane * 8] = u0.v;
  *(f16x8*)&agg[(size_t)n * 1024 + 512 + lane * 8] = u1.v;
}

// ---------------- SAGE-1 GEMM + LN + ReLU (no LDS; A-frags from global) ----------------
__global__ __launch_bounds__(256) void k_gemm(
    const _Float16* __restrict__ h0r,     // [n][16][64] root rows
    const _Float16* __restrict__ agg,     // [n][16][64] aggregated rows
    const _Float16* __restrict__ Wchi, const _Float16* __restrict__ Wclo, // [64][128]
    const float* __restrict__ b1, const float* __restrict__ g1, const float* __restrict__ be1,
    _Float16* __restrict__ Ht_all) {      // [t][n][64]
  int tid = threadIdx.x;
  int lane = tid & 63, wave = tid >> 6;
  int col16 = lane & 15, quad = lane >> 4;
  int m0 = blockIdx.x * 16;

  float bias[4], gg[4], bb[4];
  #pragma unroll
  for (int nt = 0; nt < 4; nt++) {
    int nf = nt * 16 + col16;
    bias[nt] = b1[nf]; gg[nt] = g1[nf]; bb[nt] = be1[nf];
  }
  size_t rowbase = (size_t)(m0 + col16) * 1024;

  for (int ts = 0; ts < 4; ts++) {
    int t = wave * 4 + ts;
    f32x4 acc[4];
    #pragma unroll
    for (int nt = 0; nt < 4; nt++) acc[nt] = (f32x4){0.f, 0.f, 0.f, 0.f};

    f16x8 aa[2], ar[2];
    #pragma unroll
    for (int kk = 0; kk < 2; kk++) {
      aa[kk] = *(const f16x8*)&agg[rowbase + t * 64 + kk * 32 + quad * 8];
      ar[kk] = *(const f16x8*)&h0r[rowbase + t * 64 + kk * 32 + quad * 8];
    }
    #pragma unroll
    for (int kk = 0; kk < 2; kk++) {
      #pragma unroll
      for (int nt = 0; nt < 4; nt++) {
        int nf = nt * 16 + col16;
        f16x8 bh = *(const f16x8*)&Wchi[nf * 128 + kk * 32 + quad * 8];
        f16x8 bl = *(const f16x8*)&Wclo[nf * 128 + kk * 32 + quad * 8];
        acc[nt] = __builtin_amdgcn_mfma_f32_16x16x32_f16(aa[kk], bh, acc[nt], 0, 0, 0);
        acc[nt] = __builtin_amdgcn_mfma_f32_16x16x32_f16(aa[kk], bl, acc[nt], 0, 0, 0);
      }
    }
    #pragma unroll
    for (int kk = 0; kk < 2; kk++) {
      #pragma unroll
      for (int nt = 0; nt < 4; nt++) {
        int nf = nt * 16 + col16;
        f16x8 bh = *(const f16x8*)&Wchi[nf * 128 + 64 + kk * 32 + quad * 8];
        f16x8 bl = *(const f16x8*)&Wclo[nf * 128 + 64 + kk * 32 + quad * 8];
        acc[nt] = __builtin_amdgcn_mfma_f32_16x16x32_f16(ar[kk], bh, acc[nt], 0, 0, 0);
        acc[nt] = __builtin_amdgcn_mfma_f32_16x16x32_f16(ar[kk], bl, acc[nt], 0, 0, 0);
      }
    }

    #pragma unroll
    for (int r = 0; r < 4; r++) {
      float v[4];
      #pragma unroll
      for (int nt = 0; nt < 4; nt++) v[nt] = acc[nt][r] + bias[nt];
      float s = (v[0] + v[1]) + (v[2] + v[3]);
      float mu = quad_sum16(s) * (1.f / 64.f);
      float sq = 0.f;
      #pragma unroll
      for (int nt = 0; nt < 4; nt++) { v[nt] -= mu; sq += v[nt] * v[nt]; }
      float var = quad_sum16(sq) * (1.f / 64.f);
      float rstd = rsqrtf(var + LN_EPS);
      int m = m0 + quad * 4 + r;
      size_t base = ((size_t)t * NN + m) * HG;
      #pragma unroll
      for (int nt = 0; nt < 4; nt++) {
        float o = fmaxf(v[nt] * rstd * gg[nt] + bb[nt], 0.f);
        Ht_all[base + nt * 16 + col16] = (_Float16)o;
      }
    }
  }
}

// ---------------- persistent GRU: 64 nodes/block, 8 waves (R11) ----------------
// Wave w owns gate-col tile j = w*16+col16 for all 3 gates (tiles {w,8+w,16+w}).
// Grid 313 <= 512 capacity (2 blocks/CU at 64.5 KB LDS) -> single round.
// wgh [4][3] = 48 VGPR (halved); acc[4][4] (r,z,n-ih,n-hh). hL single-buffered
// (2 barriers/t). (512,4) caps VGPR at 128 — fits (wgh 48 + temps); watch for
// spill (WRITE_SIZE) as falsifier. WihL stays in LDS (R6: global reads +45us).
__global__ __launch_bounds__(512, 4) void k_gru_all(
    const _Float16* __restrict__ Ht_all,   // [t][n][64]
    const _Float16* __restrict__ WihF,     // 384 x 64 fp16
    const _Float16* __restrict__ WhhF,     // 384 x 128 fp16
    const float* __restrict__ bih, const float* __restrict__ bhh,
    const float* __restrict__ headW, const float* __restrict__ headb,
    float* __restrict__ out) {
  __shared__ _Float16 WihL[NG * 64];       // 48 KB swizzled
  __shared__ _Float16 hL[64 * 128];        // 16 KB swizzled, single-buffered

  int tid = threadIdx.x;
  int lane = tid & 63, wave = tid >> 6;    // wave in [0,8)
  int col16 = lane & 15, quad = lane >> 4;
  int m0 = blockIdx.x * 64;

  for (int i = tid; i < NG * 8; i += 512) {
    int g = i >> 3, k8 = i & 7;
    *(f16x8*)&WihL[g * 64 + ((k8 + g) & 7) * 8] = *(const f16x8*)&WihF[g * 64 + k8 * 8];
  }
  for (int i = tid; i < 64 * 128; i += 512) hL[i] = (_Float16)0.f;

  int gts3[3] = {wave, 8 + wave, 16 + wave};   // r, z, n gate-tiles

  f16x8 wgh[4][3];
  #pragma unroll
  for (int kk = 0; kk < 4; kk++)
    #pragma unroll
    for (int g3 = 0; g3 < 3; g3++)
      wgh[kk][g3] = *(const f16x8*)&WhhF[(size_t)(gts3[g3] * 16 + col16) * HTT + kk * 32 + quad * 8];

  int j = wave * 16 + col16;
  float bR  = bih[j] + bhh[j];
  float bZ  = bih[HTT + j] + bhh[HTT + j];
  float bNi = bih[2 * HTT + j];
  float bNh = bhh[2 * HTT + j];
  float hw  = headW[j];
  int jsw = j >> 3, jlo = j & 7;

  float hreg[4][4];
  #pragma unroll
  for (int mt = 0; mt < 4; mt++)
    #pragma unroll
    for (int r = 0; r < 4; r++) hreg[mt][r] = 0.f;

  __syncthreads();

  for (int t = 0; t < TS; t++) {
    f32x4 acc[4][4];   // [r, z, n-ih, n-hh][mt]
    #pragma unroll
    for (int a = 0; a < 4; a++)
      #pragma unroll
      for (int mt = 0; mt < 4; mt++)
        acc[a][mt] = (f32x4){0.f, 0.f, 0.f, 0.f};

    // hh part (reads hL)
    #pragma unroll
    for (int kk = 0; kk < 4; kk++) {
      f16x8 ah[4];
      #pragma unroll
      for (int mt = 0; mt < 4; mt++) {
        int row = mt * 16 + col16;
        int k8 = kk * 4 + quad;
        ah[mt] = *(const f16x8*)&hL[row * 128 + ((k8 + row) & 15) * 8];
      }
      #pragma unroll
      for (int g3 = 0; g3 < 3; g3++) {
        int ai = (g3 == 2) ? 3 : g3;
        #pragma unroll
        for (int mt = 0; mt < 4; mt++)
          acc[ai][mt] = __builtin_amdgcn_mfma_f32_16x16x32_f16(ah[mt], wgh[kk][g3], acc[ai][mt], 0, 0, 0);
      }
    }

    // ih part (Ht_all from global + WihL)
    {
      const _Float16* AH = Ht_all + (size_t)t * NN * HG;
      #pragma unroll
      for (int kk = 0; kk < 2; kk++) {
        f16x8 ga[4];
        #pragma unroll
        for (int mt = 0; mt < 4; mt++) {
          int rowg = m0 + mt * 16 + col16;
          if (rowg >= NN) rowg = NN - 1;
          ga[mt] = *(const f16x8*)&AH[(size_t)rowg * HG + kk * 32 + quad * 8];
        }
        #pragma unroll
        for (int g3 = 0; g3 < 3; g3++) {
          int g = gts3[g3] * 16 + col16;
          int k8 = kk * 4 + quad;
          f16x8 b = *(const f16x8*)&WihL[g * 64 + ((k8 + g) & 7) * 8];
          int ai = (g3 == 2) ? 2 : g3;
          #pragma unroll
          for (int mt = 0; mt < 4; mt++)
            acc[ai][mt] = __builtin_amdgcn_mfma_f32_16x16x32_f16(ga[mt], b, acc[ai][mt], 0, 0, 0);
        }
      }
    }

    __syncthreads();   // all hL reads complete before overwrite

    #pragma unroll
    for (int mt = 0; mt < 4; mt++) {
      #pragma unroll
      for (int r = 0; r < 4; r++) {
        float R  = acc[0][mt][r] + bR;
        float Z  = acc[1][mt][r] + bZ;
        float Ni = acc[2][mt][r] + bNi;
        float Nh = acc[3][mt][r] + bNh;
        float rg = fast_sigmoid(R);
        float zg = fast_sigmoid(Z);
        float nn = fast_tanh(Ni + rg * Nh);
        float hn = nn + zg * (hreg[mt][r] - nn);
        hreg[mt][r] = hn;
        int row = mt * 16 + quad * 4 + r;
        hL[row * 128 + ((jsw + row) & 15) * 8 + jlo] = (_Float16)hn;
      }
    }
    __syncthreads();
  }

  // head: out[m] = sum_j hT[m][j]*headW[j] + headb. Each wave holds 16 j's.
  float* yL = (float*)hL;   // hL dead after final barrier; 2 KB alias
  #pragma unroll
  for (int mt = 0; mt < 4; mt++) {
    #pragma unroll
    for (int r = 0; r < 4; r++) {
      float py = hreg[mt][r] * hw;
      py = quad_sum16(py);
      if (col16 == 0) yL[wave * 64 + mt * 16 + quad * 4 + r] = py;
    }
  }
  __syncthreads();
  if (tid < 64 && m0 + tid < NN) {
    float s = 0.f;
    #pragma unroll
    for (int w = 0; w < 8; w++) s += yL[w * 64 + tid];
    out[m0 + tid] = s + headb[0];
  }
}

extern "C" void kernel_launch(void* const* d_in, const int* in_sizes, int n_in,
                              void* d_out, int out_size, void* d_ws, size_t ws_size,
                              hipStream_t stream) {
  const float* x_seq = (const float*)d_in[0];
  const int*   edge  = (const int*)d_in[1];
  const float* Wl0   = (const float*)d_in[2];
  const float* Wr0   = (const float*)d_in[3];
  const float* b0    = (const float*)d_in[4];
  const float* g0    = (const float*)d_in[5];
  const float* be0   = (const float*)d_in[6];
  const float* Wl1   = (const float*)d_in[7];
  const float* Wr1   = (const float*)d_in[8];
  const float* b1    = (const float*)d_in[9];
  const float* g1    = (const float*)d_in[10];
  const float* be1   = (const float*)d_in[11];
  const float* Wih   = (const float*)d_in[12];
  const float* Whh   = (const float*)d_in[13];
  const float* bih   = (const float*)d_in[14];
  const float* bhh   = (const float*)d_in[15];
  const float* headW = (const float*)d_in[16];
  const float* headb = (const float*)d_in[17];
  float* out = (float*)d_out;

  const int* srcp = edge;
  const int* dstp = edge + NE;

  char* ws = (char*)d_ws;
  size_t off = 0;
  auto alloc = [&](size_t bytes) -> void* {
    void* p = ws + off;
    off += (bytes + 255) & ~(size_t)255;
    return p;
  };
  int*   cnt     = (int*)alloc(NN * 4);
  int*   row_ptr = (int*)alloc((NN + 1) * 4);
  int*   col     = (int*)alloc(NE * 4);
  float* deg_inv = (float*)alloc(NN * 4);
  float* xT      = (float*)alloc((size_t)NN * TS * 4);
  float* P       = (float*)alloc(512 * 4);
  _Float16* h0r  = (_Float16*)alloc((size_t)NN * 1024 * 2);        // 41 MB [n][16][64]
  _Float16* code2= (_Float16*)alloc((size_t)NN * 128 * 2);         // 5.12 MB dup'd LN codes
  _Float16* agg  = (_Float16*)alloc((size_t)NN * 1024 * 2);        // 41 MB [n][16][64]
  _Float16* Ht_all = (_Float16*)alloc((size_t)TS * NN * HG * 2);   // 41 MB [t][n][64]
  _Float16* WihF = (_Float16*)alloc((size_t)NG * HG * 2);
  _Float16* WhhF = (_Float16*)alloc((size_t)NG * HTT * 2);
  _Float16* Wchi = (_Float16*)alloc((size_t)HG * 128 * 2);
  _Float16* Wclo = (_Float16*)alloc((size_t)HG * 128 * 2);
  (void)ws_size; (void)in_sizes; (void)n_in; (void)out_size;

  k_setup<<<1250, 256, 0, stream>>>(x_seq, xT, Wih, WihF, Whh, WhhF,
                                    Wl1, Wr1, Wchi, Wclo,
                                    Wl0, Wr0, b0, g0, be0, P, cnt);
  k_hist<<<(NE + 255) / 256, 256, 0, stream>>>(dstp, cnt);
  k_scan<<<1, 1024, 0, stream>>>(cnt, row_ptr, deg_inv);
  k_fill<<<(NE + 255) / 256, 256, 0, stream>>>(srcp, dstp, cnt, col);
  k_h0_fused<<<NN / 4, 256, 0, stream>>>(xT, row_ptr, col, deg_inv, P, h0r, code2);
  k_gather<<<NN / 4, 256, 0, stream>>>(row_ptr, col, code2, P, agg);
  k_gemm<<<NN / 16, 256, 0, stream>>>(h0r, agg, Wchi, Wclo, b1, g1, be1, Ht_all);
  k_gru_all<<<(NN + 63) / 64, 512, 0, stream>>>(Ht_all, WihF, WhhF, bih, bhh,
                                                headW, headb, out);
}

// Round 12
// 399.713 us; speedup vs baseline: 1.2543x; 1.2543x over previous
//
#include <hip/hip_runtime.h>
#include <math.h>

#define NN 20000
#define NE 320000
#define TS 16
#define HG 64
#define HTT 128
#define NG 384   // 3*HT
#define LN_EPS 1e-5f

typedef __attribute__((ext_vector_type(8))) _Float16 f16x8;
typedef __attribute__((ext_vector_type(4))) _Float16 f16x4;
typedef __attribute__((ext_vector_type(2))) _Float16 f16x2;
typedef __attribute__((ext_vector_type(4))) float f32x4;

__device__ __forceinline__ float wave_sum64(float v) {
  #pragma unroll
  for (int off = 32; off > 0; off >>= 1) v += __shfl_xor(v, off, 64);
  return v;
}
__device__ __forceinline__ float quad_sum16(float v) {
  #pragma unroll
  for (int off = 1; off < 16; off <<= 1) v += __shfl_xor(v, off, 64);
  return v;
}
__device__ __forceinline__ float fast_sigmoid(float x) {
  return __builtin_amdgcn_rcpf(1.f + __expf(-x));
}
__device__ __forceinline__ float fast_tanh(float x) {
  float e = __expf(-2.f * fabsf(x));
  float th = (1.f - e) * __builtin_amdgcn_rcpf(1.f + e);
  return copysignf(th, x);
}

// ============================================================================
// Journal of refuted branches (do not retry without per-kernel evidence):
//  - gru launch_bounds with ANY min-waves arg: allocator over-restricts VGPR
//    (R5: (256,4)->64 VGPR; R11: (512,4)->64 VGPR) -> full spill -> 2.5-3.7x
//    slower. PLAIN launch_bounds only on this kernel family.
//  - gru Wih from global instead of LDS: +45 us (R6).
//  - gru gah prefetch: neutral (R7).
//  - h0r elimination (reconstruct in k_gemm): +31 us (R8/R9/R10 A/B).
//  - k_gather 2-deep ping-pong: +20 us (R7 vs R4, confirmed by R10 revert).
//  - hist fused into setup + memsetAsync: neutral (R8 vs R9 A/B).
// R12: 64n/8w retile (R11, correctness-verified) with mt-OUTER loop nest:
//  acc[4] per mt-tile (16 VGPR) instead of acc[4][4] (64), gate math inside
//  the mt loop (registers only), hL writes after the read-barrier. Plain
//  __launch_bounds__(512). Peak live regs ~105 -> expect <=128 VGPR,
//  2 blocks/CU, grid 313 <= 512 slots -> single round.
// ============================================================================

// ---------------- fused setup: cnt-zero + weight cvts + moments + x transpose ----------------
__global__ __launch_bounds__(256) void k_setup(
    const float* __restrict__ x_seq, float* __restrict__ xT,
    const float* __restrict__ Wih, _Float16* __restrict__ WihF,
    const float* __restrict__ Whh, _Float16* __restrict__ WhhF,
    const float* __restrict__ Wl1, const float* __restrict__ Wr1,
    _Float16* __restrict__ Wchi, _Float16* __restrict__ Wclo,
    const float* __restrict__ Wl0, const float* __restrict__ Wr0,
    const float* __restrict__ b0, const float* __restrict__ g0,
    const float* __restrict__ be0, float* __restrict__ P,
    int* __restrict__ cnt) {
  int gid = blockIdx.x * 256 + threadIdx.x;
  int stride = gridDim.x * 256;
  for (int i = gid; i < NN * TS; i += stride) {
    int t = i / NN, n = i - t * NN;
    xT[n * 16 + t] = x_seq[i];
  }
  for (int i = gid; i < NG * HG; i += stride) WihF[i] = (_Float16)Wih[i];
  for (int i = gid; i < NG * HTT; i += stride) WhhF[i] = (_Float16)Whh[i];
  for (int i = gid; i < HG * 128; i += stride) {
    int n = i >> 7, k = i & 127;
    float x = (k < HG) ? Wl1[k * HG + n] : Wr1[(k - HG) * HG + n];
    _Float16 h = (_Float16)x;
    Wchi[i] = h;
    Wclo[i] = (_Float16)(x - (float)h);
  }
  for (int i = gid; i < NN; i += stride) cnt[i] = 0;
  if (blockIdx.x == 0 && threadIdx.x < 64) {
    int f = threadIdx.x;
    float u = Wl0[f], v = Wr0[f], c = b0[f], g = g0[f];
    float um = wave_sum64(u) * (1.f / 64.f);
    float vm = wave_sum64(v) * (1.f / 64.f);
    float cm = wave_sum64(c) * (1.f / 64.f);
    float uc = u - um, vc = v - vm, cc = c - cm;
    float muu = wave_sum64(uc * uc) * (1.f / 64.f);
    float mvv = wave_sum64(vc * vc) * (1.f / 64.f);
    float mcc = wave_sum64(cc * cc) * (1.f / 64.f);
    float muv = wave_sum64(uc * vc) * (1.f / 64.f);
    float muc = wave_sum64(uc * cc) * (1.f / 64.f);
    float mvc = wave_sum64(vc * cc) * (1.f / 64.f);
    P[f] = uc * g; P[64 + f] = vc * g; P[128 + f] = cc * g; P[192 + f] = be0[f];
    if (f == 0) {
      P[256] = muu; P[257] = mvv; P[258] = mcc;
      P[259] = muv; P[260] = muc; P[261] = mvc;
    }
  }
}

__global__ void k_hist(const int* __restrict__ dst, int* cnt) {
  int e = blockIdx.x * blockDim.x + threadIdx.x;
  if (e < NE) atomicAdd(&cnt[dst[e]], 1);
}

// 1-pass scan: thread handles 20 elements in registers
__global__ void k_scan(int* cnt, int* row_ptr, float* deg_inv) {
  __shared__ int s[1024];
  const int PER = 20;
  int tid = threadIdx.x;
  int base = tid * PER;
  int vloc[PER], dloc[PER];
  int sum = 0;
  #pragma unroll
  for (int j = 0; j < PER; j++) {
    int n = base + j;
    int d = (n < NN) ? cnt[n] : 0;
    vloc[j] = sum;
    dloc[j] = d;
    sum += d;
  }
  s[tid] = sum;
  __syncthreads();
  for (int off = 1; off < 1024; off <<= 1) {
    int t = (tid >= off) ? s[tid - off] : 0;
    __syncthreads();
    s[tid] += t;
    __syncthreads();
  }
  int excl = s[tid] - sum;
  #pragma unroll
  for (int j = 0; j < PER; j++) {
    int n = base + j;
    if (n < NN) {
      int rp = excl + vloc[j];
      row_ptr[n] = rp;
      cnt[n] = rp;
      int d = dloc[j];
      deg_inv[n] = 1.0f / (float)((d > 1) ? d : 1);
    }
  }
  if (tid == 1023) row_ptr[NN] = s[1023];
}

__global__ void k_fill(const int* __restrict__ src, const int* __restrict__ dst,
                       int* cursor, int* col) {
  int e = blockIdx.x * blockDim.x + threadIdx.x;
  if (e < NE) {
    int p = atomicAdd(&cursor[dst[e]], 1);
    col[p] = src[e];
  }
}

// ---------------- fused agg0 + h0: wave per node ----------------
// Emits per-(n,t) LN code, PRE-DUPLICATED for pk-fp16 consumption:
// code2[n][t&7][t>>3] = [A,A,X,X,C,C,0,0] (16 B), where (A,X,C) =
// (a*rstd, x*rstd, rstd); h0[n][t][f] == max(A*P[f]+X*P[64+f]+C*P[128+f]+P[192+f],0).
// 5.12 MB total -> L2-resident on every XCD. k_gather gathers THIS instead
// of the 2 KB h0 rows; h0r stays materialized for k_gemm's root rows.
__global__ __launch_bounds__(256) void k_h0_fused(
    const float* __restrict__ xT,
    const int* __restrict__ row_ptr, const int* __restrict__ col,
    const float* __restrict__ deg_inv,
    const float* __restrict__ P,
    _Float16* __restrict__ h0r,      // [n][16][64]
    _Float16* __restrict__ code2) {  // [n][8][2][8]
  int lane = threadIdx.x & 63;
  int n = blockIdx.x * 4 + (threadIdx.x >> 6);
  int grp = lane >> 4, tl = lane & 15;
  int beg = row_ptr[n];
  int deg = row_ptr[n + 1] - beg;
  float s0 = 0.f, s1 = 0.f;
  int iters = (deg + 7) >> 3;
  for (int it = 0; it < iters; it++) {
    int e0 = it * 8 + grp, e1 = it * 8 + 4 + grp;
    bool v0 = e0 < deg, v1 = e1 < deg;
    int i0 = v0 ? e0 : 0, i1 = v1 ? e1 : 0;
    int c0 = col[beg + i0];
    int c1 = col[beg + i1];
    float x0 = xT[c0 * 16 + tl];
    float x1 = xT[c1 * 16 + tl];
    s0 += v0 ? x0 : 0.f;
    s1 += v1 ? x1 : 0.f;
  }
  float s = s0 + s1;
  s += __shfl_xor(s, 16, 64);
  s += __shfl_xor(s, 32, 64);
  float aggv = s * deg_inv[n];          // lane holds agg for t = lane&15
  float xv = xT[n * 16 + tl];           // lane holds x for t = lane&15
  float muu = P[256], mvv = P[257], mcc = P[258];
  float muv = P[259], muc = P[260], mvc = P[261];
  // emit duplicated LN code for t = lane (lanes 0..15)
  if (lane < 16) {
    float a = aggv, x = xv;
    float var = a * a * muu + x * x * mvv + mcc
              + 2.f * (a * x * muv + a * muc + x * mvc);
    float rstd = rsqrtf(var + LN_EPS);
    _Float16 Ah = (_Float16)(a * rstd);
    _Float16 Xh = (_Float16)(x * rstd);
    _Float16 Ch = (_Float16)rstd;
    f16x8 cw = {Ah, Ah, Xh, Xh, Ch, Ch, (_Float16)0.f, (_Float16)0.f};
    *(f16x8*)&code2[(size_t)n * 128 + (lane & 7) * 16 + (lane >> 3) * 8] = cw;
  }
  #pragma unroll
  for (int half = 0; half < 2; half++) {
    int c = lane + half * 64;           // chunk index 0..127
    int t = c >> 3, f8 = (c & 7) * 8;
    float a = __shfl(aggv, t, 64);
    float x = __shfl(xv, t, 64);
    float var = a * a * muu + x * x * mvv + mcc
              + 2.f * (a * x * muv + a * muc + x * mvc);
    float rstd = rsqrtf(var + LN_EPS);
    f16x8 o;
    #pragma unroll
    for (int j = 0; j < 8; j++) {
      int f = f8 + j;
      float d = a * P[f] + x * P[64 + f] + P[128 + f];
      o[j] = (_Float16)fmaxf(d * rstd + P[192 + f], 0.f);
    }
    *(f16x8*)&h0r[(size_t)n * 1024 + c * 8] = o;
  }
}

// ---------------- gather/reconstruct: wave per node, no LDS ----------------
// R4 form (simple 4-edge blocks; ping-pong variant refuted +20 us).
__global__ __launch_bounds__(256) void k_gather(
    const int* __restrict__ row_ptr, const int* __restrict__ col,
    const _Float16* __restrict__ code2,  // [n][8][2][8]
    const float* __restrict__ P,
    _Float16* __restrict__ agg) {        // [n][16][64]
  int lane = threadIdx.x & 63;
  int n = blockIdx.x * 4 + (threadIdx.x >> 6);
  const f16x2 h2z = {(_Float16)0.f, (_Float16)0.f};
  const f16x2 h2o = {(_Float16)1.f, (_Float16)1.f};
  // lane covers f = f1..f1+7 at t1 = lane>>3 and t2 = 8 + (lane>>3)
  int f1 = (lane & 7) * 8;
  int tmod = lane >> 3;
  f16x2 Pu2[4], Pv2[4], Pc2[4], Pb2[4];
  #pragma unroll
  for (int j = 0; j < 4; j++) {
    Pu2[j] = (f16x2){(_Float16)P[f1 + 2*j],       (_Float16)P[f1 + 2*j + 1]};
    Pv2[j] = (f16x2){(_Float16)P[64 + f1 + 2*j],  (_Float16)P[64 + f1 + 2*j + 1]};
    Pc2[j] = (f16x2){(_Float16)P[128 + f1 + 2*j], (_Float16)P[128 + f1 + 2*j + 1]};
    Pb2[j] = (f16x2){(_Float16)P[192 + f1 + 2*j], (_Float16)P[192 + f1 + 2*j + 1]};
  }
  int beg = row_ptr[n];
  int deg = row_ptr[n + 1] - beg;
  int cvAll = (lane < deg) ? col[beg + lane] : 0;

  f16x2 aE1[4], aO1[4], aE2[4], aO2[4];
  #pragma unroll
  for (int j = 0; j < 4; j++) { aE1[j] = h2z; aO1[j] = h2z; aE2[j] = h2z; aO2[j] = h2z; }

// accumulate one duplicated code (f16x8 [A,A,X,X,C,C,_,_]) into ACC[0..3]
#define ACC_SET(c, mk, FULL, ACC)                                          \
  { f16x2 _A = __builtin_shufflevector(c, c, 0, 1);                        \
    f16x2 _X = __builtin_shufflevector(c, c, 2, 3);                        \
    f16x2 _C = __builtin_shufflevector(c, c, 4, 5);                        \
    _Pragma("unroll")                                                      \
    for (int j = 0; j < 4; j++) {                                          \
      f16x2 d = __builtin_elementwise_fma(_A, Pu2[j],                      \
                 __builtin_elementwise_fma(_X, Pv2[j],                     \
                  __builtin_elementwise_fma(_C, Pc2[j], Pb2[j])));         \
      d = __builtin_elementwise_max(d, h2z);                               \
      ACC[j] = (FULL) ? (ACC[j] + d)                                       \
                      : __builtin_elementwise_fma(d, mk, ACC[j]);          \
    } }

  int nb4 = (deg + 3) >> 2;
  if (nb4 > 16) nb4 = 16;
  for (int b = 0; b < nb4; b++) {
    int eb = b << 2;
    f16x8 cA[4], cB[4];
    #pragma unroll
    for (int e = 0; e < 4; e++) {
      int c = __builtin_amdgcn_readlane(cvAll, eb + e);
      const _Float16* cp = code2 + (size_t)c * 128 + tmod * 16;
      cA[e] = *(const f16x8*)cp;
      cB[e] = *(const f16x8*)(cp + 8);
    }
    if (eb + 4 <= deg) {
      #pragma unroll
      for (int e = 0; e < 4; e++) {
        if (e & 1) { ACC_SET(cA[e], h2o, true, aO1) ACC_SET(cB[e], h2o, true, aO2) }
        else       { ACC_SET(cA[e], h2o, true, aE1) ACC_SET(cB[e], h2o, true, aE2) }
      }
    } else {
      #pragma unroll
      for (int e = 0; e < 4; e++) {
        f16x2 mk = ((eb + e) < deg) ? h2o : h2z;
        if (e & 1) { ACC_SET(cA[e], mk, false, aO1) ACC_SET(cB[e], mk, false, aO2) }
        else       { ACC_SET(cA[e], mk, false, aE1) ACC_SET(cB[e], mk, false, aE2) }
      }
    }
  }
  for (int e = 64; e < deg; e++) {        // rare tail (deg > 64)
    int c = col[beg + e];
    const _Float16* cp = code2 + (size_t)c * 128 + tmod * 16;
    f16x8 ca = *(const f16x8*)cp;
    f16x8 cb = *(const f16x8*)(cp + 8);
    ACC_SET(ca, h2o, true, aE1) ACC_SET(cb, h2o, true, aE2)
  }
#undef ACC_SET

  float dif = 1.0f / (float)((deg > 1) ? deg : 1);
  _Float16 dih = (_Float16)dif;
  f16x2 di2 = {dih, dih};
  union { f16x8 v; f16x2 h[4]; } u0, u1;
  #pragma unroll
  for (int j = 0; j < 4; j++) {
    u0.h[j] = (aE1[j] + aO1[j]) * di2;
    u1.h[j] = (aE2[j] + aO2[j]) * di2;
  }
  *(f16x8*)&agg[(size_t)n * 1024 + lane * 8] = u0.v;
  *(f16x8*)&agg[(size_t)n * 1024 + 512 + lane * 8] = u1.v;
}

// ---------------- SAGE-1 GEMM + LN + ReLU (no LDS; A-frags from global) ----------------
__global__ __launch_bounds__(256) void k_gemm(
    const _Float16* __restrict__ h0r,     // [n][16][64] root rows
    const _Float16* __restrict__ agg,     // [n][16][64] aggregated rows
    const _Float16* __restrict__ Wchi, const _Float16* __restrict__ Wclo, // [64][128]
    const float* __restrict__ b1, const float* __restrict__ g1, const float* __restrict__ be1,
    _Float16* __restrict__ Ht_all) {      // [t][n][64]
  int tid = threadIdx.x;
  int lane = tid & 63, wave = tid >> 6;
  int col16 = lane & 15, quad = lane >> 4;
  int m0 = blockIdx.x * 16;

  float bias[4], gg[4], bb[4];
  #pragma unroll
  for (int nt = 0; nt < 4; nt++) {
    int nf = nt * 16 + col16;
    bias[nt] = b1[nf]; gg[nt] = g1[nf]; bb[nt] = be1[nf];
  }
  size_t rowbase = (size_t)(m0 + col16) * 1024;

  for (int ts = 0; ts < 4; ts++) {
    int t = wave * 4 + ts;
    f32x4 acc[4];
    #pragma unroll
    for (int nt = 0; nt < 4; nt++) acc[nt] = (f32x4){0.f, 0.f, 0.f, 0.f};

    f16x8 aa[2], ar[2];
    #pragma unroll
    for (int kk = 0; kk < 2; kk++) {
      aa[kk] = *(const f16x8*)&agg[rowbase + t * 64 + kk * 32 + quad * 8];
      ar[kk] = *(const f16x8*)&h0r[rowbase + t * 64 + kk * 32 + quad * 8];
    }
    #pragma unroll
    for (int kk = 0; kk < 2; kk++) {
      #pragma unroll
      for (int nt = 0; nt < 4; nt++) {
        int nf = nt * 16 + col16;
        f16x8 bh = *(const f16x8*)&Wchi[nf * 128 + kk * 32 + quad * 8];
        f16x8 bl = *(const f16x8*)&Wclo[nf * 128 + kk * 32 + quad * 8];
        acc[nt] = __builtin_amdgcn_mfma_f32_16x16x32_f16(aa[kk], bh, acc[nt], 0, 0, 0);
        acc[nt] = __builtin_amdgcn_mfma_f32_16x16x32_f16(aa[kk], bl, acc[nt], 0, 0, 0);
      }
    }
    #pragma unroll
    for (int kk = 0; kk < 2; kk++) {
      #pragma unroll
      for (int nt = 0; nt < 4; nt++) {
        int nf = nt * 16 + col16;
        f16x8 bh = *(const f16x8*)&Wchi[nf * 128 + 64 + kk * 32 + quad * 8];
        f16x8 bl = *(const f16x8*)&Wclo[nf * 128 + 64 + kk * 32 + quad * 8];
        acc[nt] = __builtin_amdgcn_mfma_f32_16x16x32_f16(ar[kk], bh, acc[nt], 0, 0, 0);
        acc[nt] = __builtin_amdgcn_mfma_f32_16x16x32_f16(ar[kk], bl, acc[nt], 0, 0, 0);
      }
    }

    #pragma unroll
    for (int r = 0; r < 4; r++) {
      float v[4];
      #pragma unroll
      for (int nt = 0; nt < 4; nt++) v[nt] = acc[nt][r] + bias[nt];
      float s = (v[0] + v[1]) + (v[2] + v[3]);
      float mu = quad_sum16(s) * (1.f / 64.f);
      float sq = 0.f;
      #pragma unroll
      for (int nt = 0; nt < 4; nt++) { v[nt] -= mu; sq += v[nt] * v[nt]; }
      float var = quad_sum16(sq) * (1.f / 64.f);
      float rstd = rsqrtf(var + LN_EPS);
      int m = m0 + quad * 4 + r;
      size_t base = ((size_t)t * NN + m) * HG;
      #pragma unroll
      for (int nt = 0; nt < 4; nt++) {
        float o = fmaxf(v[nt] * rstd * gg[nt] + bb[nt], 0.f);
        Ht_all[base + nt * 16 + col16] = (_Float16)o;
      }
    }
  }
}

// ---------------- persistent GRU: 64 nodes/block, 8 waves, mt-outer (R12) ----------------
// Wave w owns gate-col tile j = w*16+col16 for gates {w, 8+w, 16+w}.
// mt-OUTER nest: acc[4] per 16-node tile (16 VGPR live), gate math in-loop
// (registers only), hL writes deferred past the read-barrier. PLAIN
// launch_bounds(512) — min-waves arg refuted twice (R5, R11: VGPR->64+spill).
// Grid 313 <= 512 slots (2 blocks/CU @ 64.5 KB LDS) -> single round.
__global__ __launch_bounds__(512) void k_gru_all(
    const _Float16* __restrict__ Ht_all,   // [t][n][64]
    const _Float16* __restrict__ WihF,     // 384 x 64 fp16
    const _Float16* __restrict__ WhhF,     // 384 x 128 fp16
    const float* __restrict__ bih, const float* __restrict__ bhh,
    const float* __restrict__ headW, const float* __restrict__ headb,
    float* __restrict__ out) {
  __shared__ _Float16 WihL[NG * 64];       // 48 KB swizzled
  __shared__ _Float16 hL[64 * 128];        // 16 KB swizzled, single-buffered

  int tid = threadIdx.x;
  int lane = tid & 63, wave = tid >> 6;    // wave in [0,8)
  int col16 = lane & 15, quad = lane >> 4;
  int m0 = blockIdx.x * 64;

  for (int i = tid; i < NG * 8; i += 512) {
    int g = i >> 3, k8 = i & 7;
    *(f16x8*)&WihL[g * 64 + ((k8 + g) & 7) * 8] = *(const f16x8*)&WihF[g * 64 + k8 * 8];
  }
  for (int i = tid; i < 64 * 128; i += 512) hL[i] = (_Float16)0.f;

  int gts3[3] = {wave, 8 + wave, 16 + wave};   // r, z, n gate-tiles

  f16x8 wgh[4][3];
  #pragma unroll
  for (int kk = 0; kk < 4; kk++)
    #pragma unroll
    for (int g3 = 0; g3 < 3; g3++)
      wgh[kk][g3] = *(const f16x8*)&WhhF[(size_t)(gts3[g3] * 16 + col16) * HTT + kk * 32 + quad * 8];

  int j = wave * 16 + col16;
  float bR  = bih[j] + bhh[j];
  float bZ  = bih[HTT + j] + bhh[HTT + j];
  float bNi = bih[2 * HTT + j];
  float bNh = bhh[2 * HTT + j];
  float hw  = headW[j];
  int jsw = j >> 3, jlo = j & 7;

  float hreg[4][4];
  #pragma unroll
  for (int mt = 0; mt < 4; mt++)
    #pragma unroll
    for (int r = 0; r < 4; r++) hreg[mt][r] = 0.f;

  __syncthreads();

  for (int t = 0; t < TS; t++) {
    const _Float16* AH = Ht_all + (size_t)t * NN * HG;

    #pragma unroll
    for (int mt = 0; mt < 4; mt++) {
      f32x4 acc[4];   // r, z, n-ih, n-hh for this 16-node tile
      #pragma unroll
      for (int a = 0; a < 4; a++) acc[a] = (f32x4){0.f, 0.f, 0.f, 0.f};

      // hh part (reads hL)
      #pragma unroll
      for (int kk = 0; kk < 4; kk++) {
        int row = mt * 16 + col16;
        int k8 = kk * 4 + quad;
        f16x8 ah = *(const f16x8*)&hL[row * 128 + ((k8 + row) & 15) * 8];
        #pragma unroll
        for (int g3 = 0; g3 < 3; g3++) {
          int ai = (g3 == 2) ? 3 : g3;
          acc[ai] = __builtin_amdgcn_mfma_f32_16x16x32_f16(ah, wgh[kk][g3], acc[ai], 0, 0, 0);
        }
      }

      // ih part (Ht_all from global + WihL)
      #pragma unroll
      for (int kk = 0; kk < 2; kk++) {
        int rowg = m0 + mt * 16 + col16;
        if (rowg >= NN) rowg = NN - 1;
        f16x8 ga = *(const f16x8*)&AH[(size_t)rowg * HG + kk * 32 + quad * 8];
        #pragma unroll
        for (int g3 = 0; g3 < 3; g3++) {
          int g = gts3[g3] * 16 + col16;
          int k8 = kk * 4 + quad;
          f16x8 b = *(const f16x8*)&WihL[g * 64 + ((k8 + g) & 7) * 8];
          int ai = (g3 == 2) ? 2 : g3;
          acc[ai] = __builtin_amdgcn_mfma_f32_16x16x32_f16(ga, b, acc[ai], 0, 0, 0);
        }
      }

      // gate math (registers only; hL untouched until the barrier)
      #pragma unroll
      for (int r = 0; r < 4; r++) {
        float R  = acc[0][r] + bR;
        float Z  = acc[1][r] + bZ;
        float Ni = acc[2][r] + bNi;
        float Nh = acc[3][r] + bNh;
        float rg = fast_sigmoid(R);
        float zg = fast_sigmoid(Z);
        float nn = fast_tanh(Ni + rg * Nh);
        hreg[mt][r] = nn + zg * (hreg[mt][r] - nn);
      }
    }

    __syncthreads();   // all hL reads (every wave, every mt) complete

    #pragma unroll
    for (int mt = 0; mt < 4; mt++)
      #pragma unroll
      for (int r = 0; r < 4; r++) {
        int row = mt * 16 + quad * 4 + r;
        hL[row * 128 + ((jsw + row) & 15) * 8 + jlo] = (_Float16)hreg[mt][r];
      }
    __syncthreads();
  }

  // head: out[m] = sum_j hT[m][j]*headW[j] + headb. Each wave holds 16 j's.
  float* yL = (float*)hL;   // hL dead after final barrier; 2 KB alias
  #pragma unroll
  for (int mt = 0; mt < 4; mt++) {
    #pragma unroll
    for (int r = 0; r < 4; r++) {
      float py = hreg[mt][r] * hw;
      py = quad_sum16(py);
      if (col16 == 0) yL[wave * 64 + mt * 16 + quad * 4 + r] = py;
    }
  }
  __syncthreads();
  if (tid < 64 && m0 + tid < NN) {
    float s = 0.f;
    #pragma unroll
    for (int w = 0; w < 8; w++) s += yL[w * 64 + tid];
    out[m0 + tid] = s + headb[0];
  }
}

extern "C" void kernel_launch(void* const* d_in, const int* in_sizes, int n_in,
                              void* d_out, int out_size, void* d_ws, size_t ws_size,
                              hipStream_t stream) {
  const float* x_seq = (const float*)d_in[0];
  const int*   edge  = (const int*)d_in[1];
  const float* Wl0   = (const float*)d_in[2];
  const float* Wr0   = (const float*)d_in[3];
  const float* b0    = (const float*)d_in[4];
  const float* g0    = (const float*)d_in[5];
  const float* be0   = (const float*)d_in[6];
  const float* Wl1   = (const float*)d_in[7];
  const float* Wr1   = (const float*)d_in[8];
  const float* b1    = (const float*)d_in[9];
  const float* g1    = (const float*)d_in[10];
  const float* be1   = (const float*)d_in[11];
  const float* Wih   = (const float*)d_in[12];
  const float* Whh   = (const float*)d_in[13];
  const float* bih   = (const float*)d_in[14];
  const float* bhh   = (const float*)d_in[15];
  const float* headW = (const float*)d_in[16];
  const float* headb = (const float*)d_in[17];
  float* out = (float*)d_out;

  const int* srcp = edge;
  const int* dstp = edge + NE;

  char* ws = (char*)d_ws;
  size_t off = 0;
  auto alloc = [&](size_t bytes) -> void* {
    void* p = ws + off;
    off += (bytes + 255) & ~(size_t)255;
    return p;
  };
  int*   cnt     = (int*)alloc(NN * 4);
  int*   row_ptr = (int*)alloc((NN + 1) * 4);
  int*   col     = (int*)alloc(NE * 4);
  float* deg_inv = (float*)alloc(NN * 4);
  float* xT      = (float*)alloc((size_t)NN * TS * 4);
  float* P       = (float*)alloc(512 * 4);
  _Float16* h0r  = (_Float16*)alloc((size_t)NN * 1024 * 2);        // 41 MB [n][16][64]
  _Float16* code2= (_Float16*)alloc((size_t)NN * 128 * 2);         // 5.12 MB dup'd LN codes
  _Float16* agg  = (_Float16*)alloc((size_t)NN * 1024 * 2);        // 41 MB [n][16][64]
  _Float16* Ht_all = (_Float16*)alloc((size_t)TS * NN * HG * 2);   // 41 MB [t][n][64]
  _Float16* WihF = (_Float16*)alloc((size_t)NG * HG * 2);
  _Float16* WhhF = (_Float16*)alloc((size_t)NG * HTT * 2);
  _Float16* Wchi = (_Float16*)alloc((size_t)HG * 128 * 2);
  _Float16* Wclo = (_Float16*)alloc((size_t)HG * 128 * 2);
  (void)ws_size; (void)in_sizes; (void)n_in; (void)out_size;

  k_setup<<<1250, 256, 0, stream>>>(x_seq, xT, Wih, WihF, Whh, WhhF,
                                    Wl1, Wr1, Wchi, Wclo,
                                    Wl0, Wr0, b0, g0, be0, P, cnt);
  k_hist<<<(NE + 255) / 256, 256, 0, stream>>>(dstp, cnt);
  k_scan<<<1, 1024, 0, stream>>>(cnt, row_ptr, deg_inv);
  k_fill<<<(NE + 255) / 256, 256, 0, stream>>>(srcp, dstp, cnt, col);
  k_h0_fused<<<NN / 4, 256, 0, stream>>>(xT, row_ptr, col, deg_inv, P, h0r, code2);
  k_gather<<<NN / 4, 256, 0, stream>>>(row_ptr, col, code2, P, agg);
  k_gemm<<<NN / 16, 256, 0, stream>>>(h0r, agg, Wchi, Wclo, b1, g1, be1, Ht_all);
  k_gru_all<<<(NN + 63) / 64, 512, 0, stream>>>(Ht_all, WihF, WhhF, bih, bhh,
                                                headW, headb, out);
}

// Round 13
// 386.693 us; speedup vs baseline: 1.2965x; 1.0337x over previous
//
#include <hip/hip_runtime.h>
#include <math.h>

#define NN 20000
#define NE 320000
#define TS 16
#define HG 64
#define HTT 128
#define NG 384   // 3*HT
#define LN_EPS 1e-5f

typedef __attribute__((ext_vector_type(8))) _Float16 f16x8;
typedef __attribute__((ext_vector_type(4))) _Float16 f16x4;
typedef __attribute__((ext_vector_type(2))) _Float16 f16x2;
typedef __attribute__((ext_vector_type(4))) float f32x4;

__device__ __forceinline__ float wave_sum64(float v) {
  #pragma unroll
  for (int off = 32; off > 0; off >>= 1) v += __shfl_xor(v, off, 64);
  return v;
}
__device__ __forceinline__ float quad_sum16(float v) {
  #pragma unroll
  for (int off = 1; off < 16; off <<= 1) v += __shfl_xor(v, off, 64);
  return v;
}
__device__ __forceinline__ float fast_sigmoid(float x) {
  return __builtin_amdgcn_rcpf(1.f + __expf(-x));
}
__device__ __forceinline__ float fast_tanh(float x) {
  float e = __expf(-2.f * fabsf(x));
  float th = (1.f - e) * __builtin_amdgcn_rcpf(1.f + e);
  return copysignf(th, x);
}

// ============================================================================
// Journal of refuted branches (do not retry without per-kernel evidence):
//  - gru launch_bounds with ANY min-waves arg: VGPR forced to 64 -> full
//    spill (R5, R11). PLAIN launch_bounds only.
//  - gru mt-outer acc[4] nest: ILP 16->4 chains -> MfmaUtil 18->13.7,
//    dur 102->138 (R12). Keep acc[8][2] 16-chain per-wave structure.
//  - gru Wih from global: +45 us (R6). gah prefetch: neutral (R7).
//  - h0r elimination: +31 us (R8/R9/R10). gather ping-pong: +20 us (R7).
//  - hist fusion + memsetAsync: neutral (R8/R9).
// R13: two R10-halves per 512-thread block (waves 0-3: nodes m0..m0+31,
//  waves 4-7: m0+32..m0+63), shared WihL, hL single-buffered 64x128 with
//  deferred writes (R12-validated 2-barrier scheme). LDS 64.5 KB ->
//  2 blocks/CU; grid 313 <= 512 slots -> single round; 16 waves/CU (2x R10)
//  at identical per-wave ILP.
// ============================================================================

// ---------------- fused setup: cnt-zero + weight cvts + moments + x transpose ----------------
__global__ __launch_bounds__(256) void k_setup(
    const float* __restrict__ x_seq, float* __restrict__ xT,
    const float* __restrict__ Wih, _Float16* __restrict__ WihF,
    const float* __restrict__ Whh, _Float16* __restrict__ WhhF,
    const float* __restrict__ Wl1, const float* __restrict__ Wr1,
    _Float16* __restrict__ Wchi, _Float16* __restrict__ Wclo,
    const float* __restrict__ Wl0, const float* __restrict__ Wr0,
    const float* __restrict__ b0, const float* __restrict__ g0,
    const float* __restrict__ be0, float* __restrict__ P,
    int* __restrict__ cnt) {
  int gid = blockIdx.x * 256 + threadIdx.x;
  int stride = gridDim.x * 256;
  for (int i = gid; i < NN * TS; i += stride) {
    int t = i / NN, n = i - t * NN;
    xT[n * 16 + t] = x_seq[i];
  }
  for (int i = gid; i < NG * HG; i += stride) WihF[i] = (_Float16)Wih[i];
  for (int i = gid; i < NG * HTT; i += stride) WhhF[i] = (_Float16)Whh[i];
  for (int i = gid; i < HG * 128; i += stride) {
    int n = i >> 7, k = i & 127;
    float x = (k < HG) ? Wl1[k * HG + n] : Wr1[(k - HG) * HG + n];
    _Float16 h = (_Float16)x;
    Wchi[i] = h;
    Wclo[i] = (_Float16)(x - (float)h);
  }
  for (int i = gid; i < NN; i += stride) cnt[i] = 0;
  if (blockIdx.x == 0 && threadIdx.x < 64) {
    int f = threadIdx.x;
    float u = Wl0[f], v = Wr0[f], c = b0[f], g = g0[f];
    float um = wave_sum64(u) * (1.f / 64.f);
    float vm = wave_sum64(v) * (1.f / 64.f);
    float cm = wave_sum64(c) * (1.f / 64.f);
    float uc = u - um, vc = v - vm, cc = c - cm;
    float muu = wave_sum64(uc * uc) * (1.f / 64.f);
    float mvv = wave_sum64(vc * vc) * (1.f / 64.f);
    float mcc = wave_sum64(cc * cc) * (1.f / 64.f);
    float muv = wave_sum64(uc * vc) * (1.f / 64.f);
    float muc = wave_sum64(uc * cc) * (1.f / 64.f);
    float mvc = wave_sum64(vc * cc) * (1.f / 64.f);
    P[f] = uc * g; P[64 + f] = vc * g; P[128 + f] = cc * g; P[192 + f] = be0[f];
    if (f == 0) {
      P[256] = muu; P[257] = mvv; P[258] = mcc;
      P[259] = muv; P[260] = muc; P[261] = mvc;
    }
  }
}

__global__ void k_hist(const int* __restrict__ dst, int* cnt) {
  int e = blockIdx.x * blockDim.x + threadIdx.x;
  if (e < NE) atomicAdd(&cnt[dst[e]], 1);
}

// 1-pass scan: thread handles 20 elements in registers
__global__ void k_scan(int* cnt, int* row_ptr, float* deg_inv) {
  __shared__ int s[1024];
  const int PER = 20;
  int tid = threadIdx.x;
  int base = tid * PER;
  int vloc[PER], dloc[PER];
  int sum = 0;
  #pragma unroll
  for (int j = 0; j < PER; j++) {
    int n = base + j;
    int d = (n < NN) ? cnt[n] : 0;
    vloc[j] = sum;
    dloc[j] = d;
    sum += d;
  }
  s[tid] = sum;
  __syncthreads();
  for (int off = 1; off < 1024; off <<= 1) {
    int t = (tid >= off) ? s[tid - off] : 0;
    __syncthreads();
    s[tid] += t;
    __syncthreads();
  }
  int excl = s[tid] - sum;
  #pragma unroll
  for (int j = 0; j < PER; j++) {
    int n = base + j;
    if (n < NN) {
      int rp = excl + vloc[j];
      row_ptr[n] = rp;
      cnt[n] = rp;
      int d = dloc[j];
      deg_inv[n] = 1.0f / (float)((d > 1) ? d : 1);
    }
  }
  if (tid == 1023) row_ptr[NN] = s[1023];
}

__global__ void k_fill(const int* __restrict__ src, const int* __restrict__ dst,
                       int* cursor, int* col) {
  int e = blockIdx.x * blockDim.x + threadIdx.x;
  if (e < NE) {
    int p = atomicAdd(&cursor[dst[e]], 1);
    col[p] = src[e];
  }
}

// ---------------- fused agg0 + h0: wave per node ----------------
// Emits per-(n,t) LN code, PRE-DUPLICATED for pk-fp16 consumption:
// code2[n][t&7][t>>3] = [A,A,X,X,C,C,0,0] (16 B), where (A,X,C) =
// (a*rstd, x*rstd, rstd); h0[n][t][f] == max(A*P[f]+X*P[64+f]+C*P[128+f]+P[192+f],0).
// 5.12 MB total -> L2-resident on every XCD.
__global__ __launch_bounds__(256) void k_h0_fused(
    const float* __restrict__ xT,
    const int* __restrict__ row_ptr, const int* __restrict__ col,
    const float* __restrict__ deg_inv,
    const float* __restrict__ P,
    _Float16* __restrict__ h0r,      // [n][16][64]
    _Float16* __restrict__ code2) {  // [n][8][2][8]
  int lane = threadIdx.x & 63;
  int n = blockIdx.x * 4 + (threadIdx.x >> 6);
  int grp = lane >> 4, tl = lane & 15;
  int beg = row_ptr[n];
  int deg = row_ptr[n + 1] - beg;
  float s0 = 0.f, s1 = 0.f;
  int iters = (deg + 7) >> 3;
  for (int it = 0; it < iters; it++) {
    int e0 = it * 8 + grp, e1 = it * 8 + 4 + grp;
    bool v0 = e0 < deg, v1 = e1 < deg;
    int i0 = v0 ? e0 : 0, i1 = v1 ? e1 : 0;
    int c0 = col[beg + i0];
    int c1 = col[beg + i1];
    float x0 = xT[c0 * 16 + tl];
    float x1 = xT[c1 * 16 + tl];
    s0 += v0 ? x0 : 0.f;
    s1 += v1 ? x1 : 0.f;
  }
  float s = s0 + s1;
  s += __shfl_xor(s, 16, 64);
  s += __shfl_xor(s, 32, 64);
  float aggv = s * deg_inv[n];          // lane holds agg for t = lane&15
  float xv = xT[n * 16 + tl];           // lane holds x for t = lane&15
  float muu = P[256], mvv = P[257], mcc = P[258];
  float muv = P[259], muc = P[260], mvc = P[261];
  // emit duplicated LN code for t = lane (lanes 0..15)
  if (lane < 16) {
    float a = aggv, x = xv;
    float var = a * a * muu + x * x * mvv + mcc
              + 2.f * (a * x * muv + a * muc + x * mvc);
    float rstd = rsqrtf(var + LN_EPS);
    _Float16 Ah = (_Float16)(a * rstd);
    _Float16 Xh = (_Float16)(x * rstd);
    _Float16 Ch = (_Float16)rstd;
    f16x8 cw = {Ah, Ah, Xh, Xh, Ch, Ch, (_Float16)0.f, (_Float16)0.f};
    *(f16x8*)&code2[(size_t)n * 128 + (lane & 7) * 16 + (lane >> 3) * 8] = cw;
  }
  #pragma unroll
  for (int half = 0; half < 2; half++) {
    int c = lane + half * 64;           // chunk index 0..127
    int t = c >> 3, f8 = (c & 7) * 8;
    float a = __shfl(aggv, t, 64);
    float x = __shfl(xv, t, 64);
    float var = a * a * muu + x * x * mvv + mcc
              + 2.f * (a * x * muv + a * muc + x * mvc);
    float rstd = rsqrtf(var + LN_EPS);
    f16x8 o;
    #pragma unroll
    for (int j = 0; j < 8; j++) {
      int f = f8 + j;
      float d = a * P[f] + x * P[64 + f] + P[128 + f];
      o[j] = (_Float16)fmaxf(d * rstd + P[192 + f], 0.f);
    }
    *(f16x8*)&h0r[(size_t)n * 1024 + c * 8] = o;
  }
}

// ---------------- gather/reconstruct: wave per node, no LDS ----------------
// R4 form (simple 4-edge blocks; ping-pong variant refuted +20 us).
__global__ __launch_bounds__(256) void k_gather(
    const int* __restrict__ row_ptr, const int* __restrict__ col,
    const _Float16* __restrict__ code2,  // [n][8][2][8]
    const float* __restrict__ P,
    _Float16* __restrict__ agg) {        // [n][16][64]
  int lane = threadIdx.x & 63;
  int n = blockIdx.x * 4 + (threadIdx.x >> 6);
  const f16x2 h2z = {(_Float16)0.f, (_Float16)0.f};
  const f16x2 h2o = {(_Float16)1.f, (_Float16)1.f};
  // lane covers f = f1..f1+7 at t1 = lane>>3 and t2 = 8 + (lane>>3)
  int f1 = (lane & 7) * 8;
  int tmod = lane >> 3;
  f16x2 Pu2[4], Pv2[4], Pc2[4], Pb2[4];
  #pragma unroll
  for (int j = 0; j < 4; j++) {
    Pu2[j] = (f16x2){(_Float16)P[f1 + 2*j],       (_Float16)P[f1 + 2*j + 1]};
    Pv2[j] = (f16x2){(_Float16)P[64 + f1 + 2*j],  (_Float16)P[64 + f1 + 2*j + 1]};
    Pc2[j] = (f16x2){(_Float16)P[128 + f1 + 2*j], (_Float16)P[128 + f1 + 2*j + 1]};
    Pb2[j] = (f16x2){(_Float16)P[192 + f1 + 2*j], (_Float16)P[192 + f1 + 2*j + 1]};
  }
  int beg = row_ptr[n];
  int deg = row_ptr[n + 1] - beg;
  int cvAll = (lane < deg) ? col[beg + lane] : 0;

  f16x2 aE1[4], aO1[4], aE2[4], aO2[4];
  #pragma unroll
  for (int j = 0; j < 4; j++) { aE1[j] = h2z; aO1[j] = h2z; aE2[j] = h2z; aO2[j] = h2z; }

// accumulate one duplicated code (f16x8 [A,A,X,X,C,C,_,_]) into ACC[0..3]
#define ACC_SET(c, mk, FULL, ACC)                                          \
  { f16x2 _A = __builtin_shufflevector(c, c, 0, 1);                        \
    f16x2 _X = __builtin_shufflevector(c, c, 2, 3);                        \
    f16x2 _C = __builtin_shufflevector(c, c, 4, 5);                        \
    _Pragma("unroll")                                                      \
    for (int j = 0; j < 4; j++) {                                          \
      f16x2 d = __builtin_elementwise_fma(_A, Pu2[j],                      \
                 __builtin_elementwise_fma(_X, Pv2[j],                     \
                  __builtin_elementwise_fma(_C, Pc2[j], Pb2[j])));         \
      d = __builtin_elementwise_max(d, h2z);                               \
      ACC[j] = (FULL) ? (ACC[j] + d)                                       \
                      : __builtin_elementwise_fma(d, mk, ACC[j]);          \
    } }

  int nb4 = (deg + 3) >> 2;
  if (nb4 > 16) nb4 = 16;
  for (int b = 0; b < nb4; b++) {
    int eb = b << 2;
    f16x8 cA[4], cB[4];
    #pragma unroll
    for (int e = 0; e < 4; e++) {
      int c = __builtin_amdgcn_readlane(cvAll, eb + e);
      const _Float16* cp = code2 + (size_t)c * 128 + tmod * 16;
      cA[e] = *(const f16x8*)cp;
      cB[e] = *(const f16x8*)(cp + 8);
    }
    if (eb + 4 <= deg) {
      #pragma unroll
      for (int e = 0; e < 4; e++) {
        if (e & 1) { ACC_SET(cA[e], h2o, true, aO1) ACC_SET(cB[e], h2o, true, aO2) }
        else       { ACC_SET(cA[e], h2o, true, aE1) ACC_SET(cB[e], h2o, true, aE2) }
      }
    } else {
      #pragma unroll
      for (int e = 0; e < 4; e++) {
        f16x2 mk = ((eb + e) < deg) ? h2o : h2z;
        if (e & 1) { ACC_SET(cA[e], mk, false, aO1) ACC_SET(cB[e], mk, false, aO2) }
        else       { ACC_SET(cA[e], mk, false, aE1) ACC_SET(cB[e], mk, false, aE2) }
      }
    }
  }
  for (int e = 64; e < deg; e++) {        // rare tail (deg > 64)
    int c = col[beg + e];
    const _Float16* cp = code2 + (size_t)c * 128 + tmod * 16;
    f16x8 ca = *(const f16x8*)cp;
    f16x8 cb = *(const f16x8*)(cp + 8);
    ACC_SET(ca, h2o, true, aE1) ACC_SET(cb, h2o, true, aE2)
  }
#undef ACC_SET

  float dif = 1.0f / (float)((deg > 1) ? deg : 1);
  _Float16 dih = (_Float16)dif;
  f16x2 di2 = {dih, dih};
  union { f16x8 v; f16x2 h[4]; } u0, u1;
  #pragma unroll
  for (int j = 0; j < 4; j++) {
    u0.h[j] = (aE1[j] + aO1[j]) * di2;
    u1.h[j] = (aE2[j] + aO2[j]) * di2;
  }
  *(f16x8*)&agg[(size_t)n * 1024 + lane * 8] = u0.v;
  *(f16x8*)&agg[(size_t)n * 1024 + 512 + lane * 8] = u1.v;
}

// ---------------- SAGE-1 GEMM + LN + ReLU (no LDS; A-frags from global) ----------------
__global__ __launch_bounds__(256) void k_gemm(
    const _Float16* __restrict__ h0r,     // [n][16][64] root rows
    const _Float16* __restrict__ agg,     // [n][16][64] aggregated rows
    const _Float16* __restrict__ Wchi, const _Float16* __restrict__ Wclo, // [64][128]
    const float* __restrict__ b1, const float* __restrict__ g1, const float* __restrict__ be1,
    _Float16* __restrict__ Ht_all) {      // [t][n][64]
  int tid = threadIdx.x;
  int lane = tid & 63, wave = tid >> 6;
  int col16 = lane & 15, quad = lane >> 4;
  int m0 = blockIdx.x * 16;

  float bias[4], gg[4], bb[4];
  #pragma unroll
  for (int nt = 0; nt < 4; nt++) {
    int nf = nt * 16 + col16;
    bias[nt] = b1[nf]; gg[nt] = g1[nf]; bb[nt] = be1[nf];
  }
  size_t rowbase = (size_t)(m0 + col16) * 1024;

  for (int ts = 0; ts < 4; ts++) {
    int t = wave * 4 + ts;
    f32x4 acc[4];
    #pragma unroll
    for (int nt = 0; nt < 4; nt++) acc[nt] = (f32x4){0.f, 0.f, 0.f, 0.f};

    f16x8 aa[2], ar[2];
    #pragma unroll
    for (int kk = 0; kk < 2; kk++) {
      aa[kk] = *(const f16x8*)&agg[rowbase + t * 64 + kk * 32 + quad * 8];
      ar[kk] = *(const f16x8*)&h0r[rowbase + t * 64 + kk * 32 + quad * 8];
    }
    #pragma unroll
    for (int kk = 0; kk < 2; kk++) {
      #pragma unroll
      for (int nt = 0; nt < 4; nt++) {
        int nf = nt * 16 + col16;
        f16x8 bh = *(const f16x8*)&Wchi[nf * 128 + kk * 32 + quad * 8];
        f16x8 bl = *(const f16x8*)&Wclo[nf * 128 + kk * 32 + quad * 8];
        acc[nt] = __builtin_amdgcn_mfma_f32_16x16x32_f16(aa[kk], bh, acc[nt], 0, 0, 0);
        acc[nt] = __builtin_amdgcn_mfma_f32_16x16x32_f16(aa[kk], bl, acc[nt], 0, 0, 0);
      }
    }
    #pragma unroll
    for (int kk = 0; kk < 2; kk++) {
      #pragma unroll
      for (int nt = 0; nt < 4; nt++) {
        int nf = nt * 16 + col16;
        f16x8 bh = *(const f16x8*)&Wchi[nf * 128 + 64 + kk * 32 + quad * 8];
        f16x8 bl = *(const f16x8*)&Wclo[nf * 128 + 64 + kk * 32 + quad * 8];
        acc[nt] = __builtin_amdgcn_mfma_f32_16x16x32_f16(ar[kk], bh, acc[nt], 0, 0, 0);
        acc[nt] = __builtin_amdgcn_mfma_f32_16x16x32_f16(ar[kk], bl, acc[nt], 0, 0, 0);
      }
    }

    #pragma unroll
    for (int r = 0; r < 4; r++) {
      float v[4];
      #pragma unroll
      for (int nt = 0; nt < 4; nt++) v[nt] = acc[nt][r] + bias[nt];
      float s = (v[0] + v[1]) + (v[2] + v[3]);
      float mu = quad_sum16(s) * (1.f / 64.f);
      float sq = 0.f;
      #pragma unroll
      for (int nt = 0; nt < 4; nt++) { v[nt] -= mu; sq += v[nt] * v[nt]; }
      float var = quad_sum16(sq) * (1.f / 64.f);
      float rstd = rsqrtf(var + LN_EPS);
      int m = m0 + quad * 4 + r;
      size_t base = ((size_t)t * NN + m) * HG;
      #pragma unroll
      for (int nt = 0; nt < 4; nt++) {
        float o = fmaxf(v[nt] * rstd * gg[nt] + bb[nt], 0.f);
        Ht_all[base + nt * 16 + col16] = (_Float16)o;
      }
    }
  }
}

// ---------------- persistent GRU: 2x R10-halves per 512-thread block (R13) ----------------
// Waves 0-3: nodes [m0, m0+32); waves 4-7: [m0+32, m0+64). Each wave runs
// the EXACT R10 inner structure (6 gate-tiles, acc[8][2] = 16 chains).
// Shared WihL (48 KB); hL single-buffered 64x128 (16 KB, deferred writes,
// 2 barriers/t — R12-validated). PLAIN launch_bounds(512): min-waves arg
// refuted twice (R5,R11 VGPR->64 spill). Grid 313 <= 512 slots (2 blk/CU
// @ 64.5 KB) -> single round, 16 waves/CU.
__global__ __launch_bounds__(512) void k_gru_all(
    const _Float16* __restrict__ Ht_all,   // [t][n][64]
    const _Float16* __restrict__ WihF,     // 384 x 64 fp16
    const _Float16* __restrict__ WhhF,     // 384 x 128 fp16
    const float* __restrict__ bih, const float* __restrict__ bhh,
    const float* __restrict__ headW, const float* __restrict__ headb,
    float* __restrict__ out) {
  __shared__ _Float16 WihL[NG * 64];       // 48 KB swizzled
  __shared__ _Float16 hL[64 * 128];        // 16 KB swizzled, single-buffered
  __shared__ float yL[8][32];              // 1 KB

  int tid = threadIdx.x;
  int lane = tid & 63, wave = tid >> 6;    // wave in [0,8)
  int half = wave >> 2, w4 = wave & 3;
  int col16 = lane & 15, quad = lane >> 4;
  int m0 = blockIdx.x * 64 + half * 32;    // this half's 32-node base
  int rbase = half * 32;                   // this half's hL row base
  int gb = 2 * w4;

  for (int i = tid; i < NG * 8; i += 512) {
    int g = i >> 3, k8 = i & 7;
    *(f16x8*)&WihL[g * 64 + ((k8 + g) & 7) * 8] = *(const f16x8*)&WihF[g * 64 + k8 * 8];
  }
  for (int i = tid; i < 64 * 128; i += 512) hL[i] = (_Float16)0.f;

  int gts[6];
  #pragma unroll
  for (int t6 = 0; t6 < 6; t6++)
    gts[t6] = (t6 < 2) ? (gb + t6) : (t6 < 4) ? (8 + gb + t6 - 2) : (16 + gb + t6 - 4);

  f16x8 wgh[4][6];
  #pragma unroll
  for (int kk = 0; kk < 4; kk++)
    #pragma unroll
    for (int t6 = 0; t6 < 6; t6++)
      wgh[kk][t6] = *(const f16x8*)&WhhF[(size_t)(gts[t6] * 16 + col16) * HTT + kk * 32 + quad * 8];

  float bR[2], bZ[2], bNi[2], bNh[2], hw[2];
  int waddr[2][4][2];
  #pragma unroll
  for (int js = 0; js < 2; js++) {
    int j = (gb + js) * 16 + col16;
    bR[js]  = bih[j] + bhh[j];
    bZ[js]  = bih[HTT + j] + bhh[HTT + j];
    bNi[js] = bih[2 * HTT + j];
    bNh[js] = bhh[2 * HTT + j];
    hw[js]  = headW[j];
    #pragma unroll
    for (int mt = 0; mt < 2; mt++)
      #pragma unroll
      for (int r = 0; r < 4; r++) {
        int row = rbase + mt * 16 + quad * 4 + r;
        waddr[mt][r][js] = row * 128 + (((j >> 3) + row) & 15) * 8 + (j & 7);
      }
  }
  float hreg[2][4][2];
  #pragma unroll
  for (int mt = 0; mt < 2; mt++)
    #pragma unroll
    for (int r = 0; r < 4; r++) { hreg[mt][r][0] = 0.f; hreg[mt][r][1] = 0.f; }

  size_t aoff[2][2];
  #pragma unroll
  for (int kk = 0; kk < 2; kk++)
    #pragma unroll
    for (int mt = 0; mt < 2; mt++) {
      int rowg = m0 + mt * 16 + col16;
      if (rowg >= NN) rowg = NN - 1;       // last block guard (20032 > NN)
      aoff[kk][mt] = (size_t)rowg * HG + kk * 32 + quad * 8;
    }

  __syncthreads();

  for (int t = 0; t < TS; t++) {
    f32x4 acc[8][2];
    #pragma unroll
    for (int a = 0; a < 8; a++) {
      acc[a][0] = (f32x4){0.f, 0.f, 0.f, 0.f};
      acc[a][1] = (f32x4){0.f, 0.f, 0.f, 0.f};
    }

    const _Float16* AH = Ht_all + (size_t)t * NN * HG;
    f16x8 gah[2][2];
    #pragma unroll
    for (int kk = 0; kk < 2; kk++)
      #pragma unroll
      for (int mt = 0; mt < 2; mt++)
        gah[kk][mt] = *(const f16x8*)&AH[aoff[kk][mt]];

    #pragma unroll
    for (int kk = 0; kk < 4; kk++) {
      f16x8 ah[2];
      #pragma unroll
      for (int mt = 0; mt < 2; mt++) {
        int row = rbase + mt * 16 + col16;
        int k8 = kk * 4 + quad;
        ah[mt] = *(const f16x8*)&hL[row * 128 + ((k8 + row) & 15) * 8];
      }
      #pragma unroll
      for (int t6 = 0; t6 < 6; t6++) {
        int ai = (t6 < 4) ? t6 : t6 + 2;
        #pragma unroll
        for (int mt = 0; mt < 2; mt++)
          acc[ai][mt] = __builtin_amdgcn_mfma_f32_16x16x32_f16(ah[mt], wgh[kk][t6], acc[ai][mt], 0, 0, 0);
      }
    }
    #pragma unroll
    for (int kk = 0; kk < 2; kk++) {
      #pragma unroll
      for (int t6 = 0; t6 < 6; t6++) {
        int g = gts[t6] * 16 + col16;
        int k8 = kk * 4 + quad;
        f16x8 b = *(const f16x8*)&WihL[g * 64 + ((k8 + g) & 7) * 8];
        #pragma unroll
        for (int mt = 0; mt < 2; mt++)
          acc[t6][mt] = __builtin_amdgcn_mfma_f32_16x16x32_f16(gah[kk][mt], b, acc[t6][mt], 0, 0, 0);
      }
    }

    // gate math into registers only; hL writes deferred past the read-barrier
    #pragma unroll
    for (int mt = 0; mt < 2; mt++) {
      #pragma unroll
      for (int r = 0; r < 4; r++) {
        #pragma unroll
        for (int js = 0; js < 2; js++) {
          float R  = acc[0 + js][mt][r] + bR[js];
          float Z  = acc[2 + js][mt][r] + bZ[js];
          float Ni = acc[4 + js][mt][r] + bNi[js];
          float Nh = acc[6 + js][mt][r] + bNh[js];
          float rg = fast_sigmoid(R);
          float zg = fast_sigmoid(Z);
          float nn = fast_tanh(Ni + rg * Nh);
          hreg[mt][r][js] = nn + zg * (hreg[mt][r][js] - nn);
        }
      }
    }

    __syncthreads();   // all hL reads complete before overwrite

    #pragma unroll
    for (int mt = 0; mt < 2; mt++)
      #pragma unroll
      for (int r = 0; r < 4; r++)
        #pragma unroll
        for (int js = 0; js < 2; js++)
          hL[waddr[mt][r][js]] = (_Float16)hreg[mt][r][js];
    __syncthreads();
  }

  #pragma unroll
  for (int mt = 0; mt < 2; mt++) {
    #pragma unroll
    for (int r = 0; r < 4; r++) {
      float py = hreg[mt][r][0] * hw[0] + hreg[mt][r][1] * hw[1];
      py = quad_sum16(py);
      if (col16 == 0) yL[wave][mt * 16 + quad * 4 + r] = py;
    }
  }
  __syncthreads();
  if (tid < 64) {
    int n = blockIdx.x * 64 + tid;
    if (n < NN) {
      int ho = (tid >> 5) * 4;      // waves of this half
      int idx = tid & 31;
      out[n] = yL[ho + 0][idx] + yL[ho + 1][idx] + yL[ho + 2][idx] + yL[ho + 3][idx] + headb[0];
    }
  }
}

extern "C" void kernel_launch(void* const* d_in, const int* in_sizes, int n_in,
                              void* d_out, int out_size, void* d_ws, size_t ws_size,
                              hipStream_t stream) {
  const float* x_seq = (const float*)d_in[0];
  const int*   edge  = (const int*)d_in[1];
  const float* Wl0   = (const float*)d_in[2];
  const float* Wr0   = (const float*)d_in[3];
  const float* b0    = (const float*)d_in[4];
  const float* g0    = (const float*)d_in[5];
  const float* be0   = (const float*)d_in[6];
  const float* Wl1   = (const float*)d_in[7];
  const float* Wr1   = (const float*)d_in[8];
  const float* b1    = (const float*)d_in[9];
  const float* g1    = (const float*)d_in[10];
  const float* be1   = (const float*)d_in[11];
  const float* Wih   = (const float*)d_in[12];
  const float* Whh   = (const float*)d_in[13];
  const float* bih   = (const float*)d_in[14];
  const float* bhh   = (const float*)d_in[15];
  const float* headW = (const float*)d_in[16];
  const float* headb = (const float*)d_in[17];
  float* out = (float*)d_out;

  const int* srcp = edge;
  const int* dstp = edge + NE;

  char* ws = (char*)d_ws;
  size_t off = 0;
  auto alloc = [&](size_t bytes) -> void* {
    void* p = ws + off;
    off += (bytes + 255) & ~(size_t)255;
    return p;
  };
  int*   cnt     = (int*)alloc(NN * 4);
  int*   row_ptr = (int*)alloc((NN + 1) * 4);
  int*   col     = (int*)alloc(NE * 4);
  float* deg_inv = (float*)alloc(NN * 4);
  float* xT      = (float*)alloc((size_t)NN * TS * 4);
  float* P       = (float*)alloc(512 * 4);
  _Float16* h0r  = (_Float16*)alloc((size_t)NN * 1024 * 2);        // 41 MB [n][16][64]
  _Float16* code2= (_Float16*)alloc((size_t)NN * 128 * 2);         // 5.12 MB dup'd LN codes
  _Float16* agg  = (_Float16*)alloc((size_t)NN * 1024 * 2);        // 41 MB [n][16][64]
  _Float16* Ht_all = (_Float16*)alloc((size_t)TS * NN * HG * 2);   // 41 MB [t][n][64]
  _Float16* WihF = (_Float16*)alloc((size_t)NG * HG * 2);
  _Float16* WhhF = (_Float16*)alloc((size_t)NG * HTT * 2);
  _Float16* Wchi = (_Float16*)alloc((size_t)HG * 128 * 2);
  _Float16* Wclo = (_Float16*)alloc((size_t)HG * 128 * 2);
  (void)ws_size; (void)in_sizes; (void)n_in; (void)out_size;

  k_setup<<<1250, 256, 0, stream>>>(x_seq, xT, Wih, WihF, Whh, WhhF,
                                    Wl1, Wr1, Wchi, Wclo,
                                    Wl0, Wr0, b0, g0, be0, P, cnt);
  k_hist<<<(NE + 255) / 256, 256, 0, stream>>>(dstp, cnt);
  k_scan<<<1, 1024, 0, stream>>>(cnt, row_ptr, deg_inv);
  k_fill<<<(NE + 255) / 256, 256, 0, stream>>>(srcp, dstp, cnt, col);
  k_h0_fused<<<NN / 4, 256, 0, stream>>>(xT, row_ptr, col, deg_inv, P, h0r, code2);
  k_gather<<<NN / 4, 256, 0, stream>>>(row_ptr, col, code2, P, agg);
  k_gemm<<<NN / 16, 256, 0, stream>>>(h0r, agg, Wchi, Wclo, b1, g1, be1, Ht_all);
  k_gru_all<<<(NN + 63) / 64, 512, 0, stream>>>(Ht_all, WihF, WhhF, bih, bhh,
                                                headW, headb, out);
}

// Round 14
// 360.249 us; speedup vs baseline: 1.3917x; 1.0734x over previous
//
#include <hip/hip_runtime.h>
#include <math.h>

#define NN 20000
#define NE 320000
#define TS 16
#define HG 64
#define HTT 128
#define NG 384   // 3*HT
#define LN_EPS 1e-5f

typedef __attribute__((ext_vector_type(8))) _Float16 f16x8;
typedef __attribute__((ext_vector_type(4))) _Float16 f16x4;
typedef __attribute__((ext_vector_type(2))) _Float16 f16x2;
typedef __attribute__((ext_vector_type(4))) float f32x4;

__device__ __forceinline__ float wave_sum64(float v) {
  #pragma unroll
  for (int off = 32; off > 0; off >>= 1) v += __shfl_xor(v, off, 64);
  return v;
}
__device__ __forceinline__ float quad_sum16(float v) {
  #pragma unroll
  for (int off = 1; off < 16; off <<= 1) v += __shfl_xor(v, off, 64);
  return v;
}
__device__ __forceinline__ float fast_sigmoid(float x) {
  return __builtin_amdgcn_rcpf(1.f + __expf(-x));
}
__device__ __forceinline__ float fast_tanh(float x) {
  float e = __expf(-2.f * fabsf(x));
  float th = (1.f - e) * __builtin_amdgcn_rcpf(1.f + e);
  return copysignf(th, x);
}

// ============================================================================
// FINAL (R14): byte-identical revert to R10 = best-measured 363.5 us.
// Journal of refuted branches (do not retry without per-kernel evidence):
//  - gru launch_bounds with ANY min-waves arg: VGPR forced to 64 -> full
//    spill (R5: (256,4); R11: (512,4)). PLAIN launch_bounds only.
//  - gru mt-outer acc[4] nest: ILP 16->4 chains -> dur 102->138 (R12).
//  - gru 64n/8w two-half block: 313 blocks = 1.22/CU -> 57 CUs get 2 blocks
//    (2x critical path) + doubled barrier scope -> 125 us (R13).
//  - gru Wih from global: +45 us (R6). gah prefetch: neutral (R7).
//  - h0r elimination (reconstruct in k_gemm): +31 us (R8/R9/R10 A/B).
//  - k_gather 2-deep ping-pong: +20 us (R7 vs R4, confirmed by R10 revert).
//  - hist fusion + memsetAsync: neutral (R8 vs R9 A/B).
// k_gru_all @102us ledger: R10-form 102 vs variants 148/375/139/125 —
// the 2-blocks/CU, 16-chain, 625-block config is a sharp local optimum.
// ============================================================================

// ---------------- fused setup: cnt-zero + weight cvts + moments + x transpose ----------------
__global__ __launch_bounds__(256) void k_setup(
    const float* __restrict__ x_seq, float* __restrict__ xT,
    const float* __restrict__ Wih, _Float16* __restrict__ WihF,
    const float* __restrict__ Whh, _Float16* __restrict__ WhhF,
    const float* __restrict__ Wl1, const float* __restrict__ Wr1,
    _Float16* __restrict__ Wchi, _Float16* __restrict__ Wclo,
    const float* __restrict__ Wl0, const float* __restrict__ Wr0,
    const float* __restrict__ b0, const float* __restrict__ g0,
    const float* __restrict__ be0, float* __restrict__ P,
    int* __restrict__ cnt) {
  int gid = blockIdx.x * 256 + threadIdx.x;
  int stride = gridDim.x * 256;
  for (int i = gid; i < NN * TS; i += stride) {
    int t = i / NN, n = i - t * NN;
    xT[n * 16 + t] = x_seq[i];
  }
  for (int i = gid; i < NG * HG; i += stride) WihF[i] = (_Float16)Wih[i];
  for (int i = gid; i < NG * HTT; i += stride) WhhF[i] = (_Float16)Whh[i];
  for (int i = gid; i < HG * 128; i += stride) {
    int n = i >> 7, k = i & 127;
    float x = (k < HG) ? Wl1[k * HG + n] : Wr1[(k - HG) * HG + n];
    _Float16 h = (_Float16)x;
    Wchi[i] = h;
    Wclo[i] = (_Float16)(x - (float)h);
  }
  for (int i = gid; i < NN; i += stride) cnt[i] = 0;
  if (blockIdx.x == 0 && threadIdx.x < 64) {
    int f = threadIdx.x;
    float u = Wl0[f], v = Wr0[f], c = b0[f], g = g0[f];
    float um = wave_sum64(u) * (1.f / 64.f);
    float vm = wave_sum64(v) * (1.f / 64.f);
    float cm = wave_sum64(c) * (1.f / 64.f);
    float uc = u - um, vc = v - vm, cc = c - cm;
    float muu = wave_sum64(uc * uc) * (1.f / 64.f);
    float mvv = wave_sum64(vc * vc) * (1.f / 64.f);
    float mcc = wave_sum64(cc * cc) * (1.f / 64.f);
    float muv = wave_sum64(uc * vc) * (1.f / 64.f);
    float muc = wave_sum64(uc * cc) * (1.f / 64.f);
    float mvc = wave_sum64(vc * cc) * (1.f / 64.f);
    P[f] = uc * g; P[64 + f] = vc * g; P[128 + f] = cc * g; P[192 + f] = be0[f];
    if (f == 0) {
      P[256] = muu; P[257] = mvv; P[258] = mcc;
      P[259] = muv; P[260] = muc; P[261] = mvc;
    }
  }
}

__global__ void k_hist(const int* __restrict__ dst, int* cnt) {
  int e = blockIdx.x * blockDim.x + threadIdx.x;
  if (e < NE) atomicAdd(&cnt[dst[e]], 1);
}

// 1-pass scan: thread handles 20 elements in registers
__global__ void k_scan(int* cnt, int* row_ptr, float* deg_inv) {
  __shared__ int s[1024];
  const int PER = 20;
  int tid = threadIdx.x;
  int base = tid * PER;
  int vloc[PER], dloc[PER];
  int sum = 0;
  #pragma unroll
  for (int j = 0; j < PER; j++) {
    int n = base + j;
    int d = (n < NN) ? cnt[n] : 0;
    vloc[j] = sum;
    dloc[j] = d;
    sum += d;
  }
  s[tid] = sum;
  __syncthreads();
  for (int off = 1; off < 1024; off <<= 1) {
    int t = (tid >= off) ? s[tid - off] : 0;
    __syncthreads();
    s[tid] += t;
    __syncthreads();
  }
  int excl = s[tid] - sum;
  #pragma unroll
  for (int j = 0; j < PER; j++) {
    int n = base + j;
    if (n < NN) {
      int rp = excl + vloc[j];
      row_ptr[n] = rp;
      cnt[n] = rp;
      int d = dloc[j];
      deg_inv[n] = 1.0f / (float)((d > 1) ? d : 1);
    }
  }
  if (tid == 1023) row_ptr[NN] = s[1023];
}

__global__ void k_fill(const int* __restrict__ src, const int* __restrict__ dst,
                       int* cursor, int* col) {
  int e = blockIdx.x * blockDim.x + threadIdx.x;
  if (e < NE) {
    int p = atomicAdd(&cursor[dst[e]], 1);
    col[p] = src[e];
  }
}

// ---------------- fused agg0 + h0: wave per node ----------------
// Emits per-(n,t) LN code, PRE-DUPLICATED for pk-fp16 consumption:
// code2[n][t&7][t>>3] = [A,A,X,X,C,C,0,0] (16 B), where (A,X,C) =
// (a*rstd, x*rstd, rstd); h0[n][t][f] == max(A*P[f]+X*P[64+f]+C*P[128+f]+P[192+f],0).
// 5.12 MB total -> L2-resident on every XCD. k_gather gathers THIS instead
// of the 2 KB h0 rows; h0r stays materialized for k_gemm's root rows.
__global__ __launch_bounds__(256) void k_h0_fused(
    const float* __restrict__ xT,
    const int* __restrict__ row_ptr, const int* __restrict__ col,
    const float* __restrict__ deg_inv,
    const float* __restrict__ P,
    _Float16* __restrict__ h0r,      // [n][16][64]
    _Float16* __restrict__ code2) {  // [n][8][2][8]
  int lane = threadIdx.x & 63;
  int n = blockIdx.x * 4 + (threadIdx.x >> 6);
  int grp = lane >> 4, tl = lane & 15;
  int beg = row_ptr[n];
  int deg = row_ptr[n + 1] - beg;
  float s0 = 0.f, s1 = 0.f;
  int iters = (deg + 7) >> 3;
  for (int it = 0; it < iters; it++) {
    int e0 = it * 8 + grp, e1 = it * 8 + 4 + grp;
    bool v0 = e0 < deg, v1 = e1 < deg;
    int i0 = v0 ? e0 : 0, i1 = v1 ? e1 : 0;
    int c0 = col[beg + i0];
    int c1 = col[beg + i1];
    float x0 = xT[c0 * 16 + tl];
    float x1 = xT[c1 * 16 + tl];
    s0 += v0 ? x0 : 0.f;
    s1 += v1 ? x1 : 0.f;
  }
  float s = s0 + s1;
  s += __shfl_xor(s, 16, 64);
  s += __shfl_xor(s, 32, 64);
  float aggv = s * deg_inv[n];          // lane holds agg for t = lane&15
  float xv = xT[n * 16 + tl];           // lane holds x for t = lane&15
  float muu = P[256], mvv = P[257], mcc = P[258];
  float muv = P[259], muc = P[260], mvc = P[261];
  // emit duplicated LN code for t = lane (lanes 0..15)
  if (lane < 16) {
    float a = aggv, x = xv;
    float var = a * a * muu + x * x * mvv + mcc
              + 2.f * (a * x * muv + a * muc + x * mvc);
    float rstd = rsqrtf(var + LN_EPS);
    _Float16 Ah = (_Float16)(a * rstd);
    _Float16 Xh = (_Float16)(x * rstd);
    _Float16 Ch = (_Float16)rstd;
    f16x8 cw = {Ah, Ah, Xh, Xh, Ch, Ch, (_Float16)0.f, (_Float16)0.f};
    *(f16x8*)&code2[(size_t)n * 128 + (lane & 7) * 16 + (lane >> 3) * 8] = cw;
  }
  #pragma unroll
  for (int half = 0; half < 2; half++) {
    int c = lane + half * 64;           // chunk index 0..127
    int t = c >> 3, f8 = (c & 7) * 8;
    float a = __shfl(aggv, t, 64);
    float x = __shfl(xv, t, 64);
    float var = a * a * muu + x * x * mvv + mcc
              + 2.f * (a * x * muv + a * muc + x * mvc);
    float rstd = rsqrtf(var + LN_EPS);
    f16x8 o;
    #pragma unroll
    for (int j = 0; j < 8; j++) {
      int f = f8 + j;
      float d = a * P[f] + x * P[64 + f] + P[128 + f];
      o[j] = (_Float16)fmaxf(d * rstd + P[192 + f], 0.f);
    }
    *(f16x8*)&h0r[(size_t)n * 1024 + c * 8] = o;
  }
}

// ---------------- gather/reconstruct: wave per node, no LDS ----------------
// R4 form (simple 4-edge blocks; ping-pong variant refuted +20 us).
__global__ __launch_bounds__(256) void k_gather(
    const int* __restrict__ row_ptr, const int* __restrict__ col,
    const _Float16* __restrict__ code2,  // [n][8][2][8]
    const float* __restrict__ P,
    _Float16* __restrict__ agg) {        // [n][16][64]
  int lane = threadIdx.x & 63;
  int n = blockIdx.x * 4 + (threadIdx.x >> 6);
  const f16x2 h2z = {(_Float16)0.f, (_Float16)0.f};
  const f16x2 h2o = {(_Float16)1.f, (_Float16)1.f};
  // lane covers f = f1..f1+7 at t1 = lane>>3 and t2 = 8 + (lane>>3)
  int f1 = (lane & 7) * 8;
  int tmod = lane >> 3;
  f16x2 Pu2[4], Pv2[4], Pc2[4], Pb2[4];
  #pragma unroll
  for (int j = 0; j < 4; j++) {
    Pu2[j] = (f16x2){(_Float16)P[f1 + 2*j],       (_Float16)P[f1 + 2*j + 1]};
    Pv2[j] = (f16x2){(_Float16)P[64 + f1 + 2*j],  (_Float16)P[64 + f1 + 2*j + 1]};
    Pc2[j] = (f16x2){(_Float16)P[128 + f1 + 2*j], (_Float16)P[128 + f1 + 2*j + 1]};
    Pb2[j] = (f16x2){(_Float16)P[192 + f1 + 2*j], (_Float16)P[192 + f1 + 2*j + 1]};
  }
  int beg = row_ptr[n];
  int deg = row_ptr[n + 1] - beg;
  int cvAll = (lane < deg) ? col[beg + lane] : 0;

  f16x2 aE1[4], aO1[4], aE2[4], aO2[4];
  #pragma unroll
  for (int j = 0; j < 4; j++) { aE1[j] = h2z; aO1[j] = h2z; aE2[j] = h2z; aO2[j] = h2z; }

// accumulate one duplicated code (f16x8 [A,A,X,X,C,C,_,_]) into ACC[0..3]
#define ACC_SET(c, mk, FULL, ACC)                                          \
  { f16x2 _A = __builtin_shufflevector(c, c, 0, 1);                        \
    f16x2 _X = __builtin_shufflevector(c, c, 2, 3);                        \
    f16x2 _C = __builtin_shufflevector(c, c, 4, 5);                        \
    _Pragma("unroll")                                                      \
    for (int j = 0; j < 4; j++) {                                          \
      f16x2 d = __builtin_elementwise_fma(_A, Pu2[j],                      \
                 __builtin_elementwise_fma(_X, Pv2[j],                     \
                  __builtin_elementwise_fma(_C, Pc2[j], Pb2[j])));         \
      d = __builtin_elementwise_max(d, h2z);                               \
      ACC[j] = (FULL) ? (ACC[j] + d)                                       \
                      : __builtin_elementwise_fma(d, mk, ACC[j]);          \
    } }

  int nb4 = (deg + 3) >> 2;
  if (nb4 > 16) nb4 = 16;
  for (int b = 0; b < nb4; b++) {
    int eb = b << 2;
    f16x8 cA[4], cB[4];
    #pragma unroll
    for (int e = 0; e < 4; e++) {
      int c = __builtin_amdgcn_readlane(cvAll, eb + e);
      const _Float16* cp = code2 + (size_t)c * 128 + tmod * 16;
      cA[e] = *(const f16x8*)cp;
      cB[e] = *(const f16x8*)(cp + 8);
    }
    if (eb + 4 <= deg) {
      #pragma unroll
      for (int e = 0; e < 4; e++) {
        if (e & 1) { ACC_SET(cA[e], h2o, true, aO1) ACC_SET(cB[e], h2o, true, aO2) }
        else       { ACC_SET(cA[e], h2o, true, aE1) ACC_SET(cB[e], h2o, true, aE2) }
      }
    } else {
      #pragma unroll
      for (int e = 0; e < 4; e++) {
        f16x2 mk = ((eb + e) < deg) ? h2o : h2z;
        if (e & 1) { ACC_SET(cA[e], mk, false, aO1) ACC_SET(cB[e], mk, false, aO2) }
        else       { ACC_SET(cA[e], mk, false, aE1) ACC_SET(cB[e], mk, false, aE2) }
      }
    }
  }
  for (int e = 64; e < deg; e++) {        // rare tail (deg > 64)
    int c = col[beg + e];
    const _Float16* cp = code2 + (size_t)c * 128 + tmod * 16;
    f16x8 ca = *(const f16x8*)cp;
    f16x8 cb = *(const f16x8*)(cp + 8);
    ACC_SET(ca, h2o, true, aE1) ACC_SET(cb, h2o, true, aE2)
  }
#undef ACC_SET

  float dif = 1.0f / (float)((deg > 1) ? deg : 1);
  _Float16 dih = (_Float16)dif;
  f16x2 di2 = {dih, dih};
  union { f16x8 v; f16x2 h[4]; } u0, u1;
  #pragma unroll
  for (int j = 0; j < 4; j++) {
    u0.h[j] = (aE1[j] + aO1[j]) * di2;
    u1.h[j] = (aE2[j] + aO2[j]) * di2;
  }
  *(f16x8*)&agg[(size_t)n * 1024 + lane * 8] = u0.v;
  *(f16x8*)&agg[(size_t)n * 1024 + 512 + lane * 8] = u1.v;
}

// ---------------- SAGE-1 GEMM + LN + ReLU (no LDS; A-frags from global) ----------------
__global__ __launch_bounds__(256) void k_gemm(
    const _Float16* __restrict__ h0r,     // [n][16][64] root rows
    const _Float16* __restrict__ agg,     // [n][16][64] aggregated rows
    const _Float16* __restrict__ Wchi, const _Float16* __restrict__ Wclo, // [64][128]
    const float* __restrict__ b1, const float* __restrict__ g1, const float* __restrict__ be1,
    _Float16* __restrict__ Ht_all) {      // [t][n][64]
  int tid = threadIdx.x;
  int lane = tid & 63, wave = tid >> 6;
  int col16 = lane & 15, quad = lane >> 4;
  int m0 = blockIdx.x * 16;

  float bias[4], gg[4], bb[4];
  #pragma unroll
  for (int nt = 0; nt < 4; nt++) {
    int nf = nt * 16 + col16;
    bias[nt] = b1[nf]; gg[nt] = g1[nf]; bb[nt] = be1[nf];
  }
  size_t rowbase = (size_t)(m0 + col16) * 1024;

  for (int ts = 0; ts < 4; ts++) {
    int t = wave * 4 + ts;
    f32x4 acc[4];
    #pragma unroll
    for (int nt = 0; nt < 4; nt++) acc[nt] = (f32x4){0.f, 0.f, 0.f, 0.f};

    f16x8 aa[2], ar[2];
    #pragma unroll
    for (int kk = 0; kk < 2; kk++) {
      aa[kk] = *(const f16x8*)&agg[rowbase + t * 64 + kk * 32 + quad * 8];
      ar[kk] = *(const f16x8*)&h0r[rowbase + t * 64 + kk * 32 + quad * 8];
    }
    #pragma unroll
    for (int kk = 0; kk < 2; kk++) {
      #pragma unroll
      for (int nt = 0; nt < 4; nt++) {
        int nf = nt * 16 + col16;
        f16x8 bh = *(const f16x8*)&Wchi[nf * 128 + kk * 32 + quad * 8];
        f16x8 bl = *(const f16x8*)&Wclo[nf * 128 + kk * 32 + quad * 8];
        acc[nt] = __builtin_amdgcn_mfma_f32_16x16x32_f16(aa[kk], bh, acc[nt], 0, 0, 0);
        acc[nt] = __builtin_amdgcn_mfma_f32_16x16x32_f16(aa[kk], bl, acc[nt], 0, 0, 0);
      }
    }
    #pragma unroll
    for (int kk = 0; kk < 2; kk++) {
      #pragma unroll
      for (int nt = 0; nt < 4; nt++) {
        int nf = nt * 16 + col16;
        f16x8 bh = *(const f16x8*)&Wchi[nf * 128 + 64 + kk * 32 + quad * 8];
        f16x8 bl = *(const f16x8*)&Wclo[nf * 128 + 64 + kk * 32 + quad * 8];
        acc[nt] = __builtin_amdgcn_mfma_f32_16x16x32_f16(ar[kk], bh, acc[nt], 0, 0, 0);
        acc[nt] = __builtin_amdgcn_mfma_f32_16x16x32_f16(ar[kk], bl, acc[nt], 0, 0, 0);
      }
    }

    #pragma unroll
    for (int r = 0; r < 4; r++) {
      float v[4];
      #pragma unroll
      for (int nt = 0; nt < 4; nt++) v[nt] = acc[nt][r] + bias[nt];
      float s = (v[0] + v[1]) + (v[2] + v[3]);
      float mu = quad_sum16(s) * (1.f / 64.f);
      float sq = 0.f;
      #pragma unroll
      for (int nt = 0; nt < 4; nt++) { v[nt] -= mu; sq += v[nt] * v[nt]; }
      float var = quad_sum16(sq) * (1.f / 64.f);
      float rstd = rsqrtf(var + LN_EPS);
      int m = m0 + quad * 4 + r;
      size_t base = ((size_t)t * NN + m) * HG;
      #pragma unroll
      for (int nt = 0; nt < 4; nt++) {
        float o = fmaxf(v[nt] * rstd * gg[nt] + bb[nt], 0.f);
        Ht_all[base + nt * 16 + col16] = (_Float16)o;
      }
    }
  }
}

// ---------------- persistent GRU (R13 version — known-good ~102 us) ----------------
// WihL in LDS (global reads cost +45 us — R6). Plain (256,2): known-good
// 128-VGPR budget. DO NOT raise min-waves: forces VGPR 64 -> full spill
// (R5, R11). Keep acc[8][2] 16-chain ILP (mt-outer refuted, R12). Keep
// 625-block grid (64n/8w two-half refuted, R13: 1.22 blocks/CU imbalance).
__global__ __launch_bounds__(256, 2) void k_gru_all(
    const _Float16* __restrict__ Ht_all,   // [t][n][64]
    const _Float16* __restrict__ WihF,     // 384 x 64 fp16
    const _Float16* __restrict__ WhhF,     // 384 x 128 fp16
    const float* __restrict__ bih, const float* __restrict__ bhh,
    const float* __restrict__ headW, const float* __restrict__ headb,
    float* __restrict__ out) {
  __shared__ _Float16 WihL[NG * 64];       // 48 KB swizzled
  __shared__ _Float16 hL[2][32 * 128];     // 2 x 8 KB swizzled
  __shared__ float yL[4][32];

  int tid = threadIdx.x;
  int lane = tid & 63, wave = tid >> 6;
  int col16 = lane & 15, quad = lane >> 4;
  int m0 = blockIdx.x * 32;
  int gb = 2 * wave;

  for (int i = tid; i < NG * 8; i += 256) {
    int g = i >> 3, k8 = i & 7;
    *(f16x8*)&WihL[g * 64 + ((k8 + g) & 7) * 8] = *(const f16x8*)&WihF[g * 64 + k8 * 8];
  }
  for (int i = tid; i < 2 * 32 * 128; i += 256) hL[0][i] = (_Float16)0.f;

  int gts[6];
  #pragma unroll
  for (int t6 = 0; t6 < 6; t6++)
    gts[t6] = (t6 < 2) ? (gb + t6) : (t6 < 4) ? (8 + gb + t6 - 2) : (16 + gb + t6 - 4);

  f16x8 wgh[4][6];
  #pragma unroll
  for (int kk = 0; kk < 4; kk++)
    #pragma unroll
    for (int t6 = 0; t6 < 6; t6++)
      wgh[kk][t6] = *(const f16x8*)&WhhF[(size_t)(gts[t6] * 16 + col16) * HTT + kk * 32 + quad * 8];

  float bR[2], bZ[2], bNi[2], bNh[2], hw[2];
  int waddr[2][4][2];
  #pragma unroll
  for (int js = 0; js < 2; js++) {
    int j = (gb + js) * 16 + col16;
    bR[js]  = bih[j] + bhh[j];
    bZ[js]  = bih[HTT + j] + bhh[HTT + j];
    bNi[js] = bih[2 * HTT + j];
    bNh[js] = bhh[2 * HTT + j];
    hw[js]  = headW[j];
    #pragma unroll
    for (int mt = 0; mt < 2; mt++)
      #pragma unroll
      for (int r = 0; r < 4; r++) {
        int row = mt * 16 + quad * 4 + r;
        waddr[mt][r][js] = row * 128 + (((j >> 3) + row) & 15) * 8 + (j & 7);
      }
  }
  float hreg[2][4][2];
  #pragma unroll
  for (int mt = 0; mt < 2; mt++)
    #pragma unroll
    for (int r = 0; r < 4; r++) { hreg[mt][r][0] = 0.f; hreg[mt][r][1] = 0.f; }

  size_t aoff[2][2];
  #pragma unroll
  for (int kk = 0; kk < 2; kk++)
    #pragma unroll
    for (int mt = 0; mt < 2; mt++)
      aoff[kk][mt] = (size_t)(m0 + mt * 16 + col16) * HG + kk * 32 + quad * 8;

  __syncthreads();

  for (int t = 0; t < TS; t++) {
    const _Float16* hcur = hL[t & 1];
    _Float16* hnxt = hL[(t + 1) & 1];

    f32x4 acc[8][2];
    #pragma unroll
    for (int a = 0; a < 8; a++) {
      acc[a][0] = (f32x4){0.f, 0.f, 0.f, 0.f};
      acc[a][1] = (f32x4){0.f, 0.f, 0.f, 0.f};
    }

    const _Float16* AH = Ht_all + (size_t)t * NN * HG;
    f16x8 gah[2][2];
    #pragma unroll
    for (int kk = 0; kk < 2; kk++)
      #pragma unroll
      for (int mt = 0; mt < 2; mt++)
        gah[kk][mt] = *(const f16x8*)&AH[aoff[kk][mt]];

    #pragma unroll
    for (int kk = 0; kk < 4; kk++) {
      f16x8 ah[2];
      #pragma unroll
      for (int mt = 0; mt < 2; mt++) {
        int row = mt * 16 + col16;
        int k8 = kk * 4 + quad;
        ah[mt] = *(const f16x8*)&hcur[row * 128 + ((k8 + row) & 15) * 8];
      }
      #pragma unroll
      for (int t6 = 0; t6 < 6; t6++) {
        int ai = (t6 < 4) ? t6 : t6 + 2;
        #pragma unroll
        for (int mt = 0; mt < 2; mt++)
          acc[ai][mt] = __builtin_amdgcn_mfma_f32_16x16x32_f16(ah[mt], wgh[kk][t6], acc[ai][mt], 0, 0, 0);
      }
    }
    #pragma unroll
    for (int kk = 0; kk < 2; kk++) {
      #pragma unroll
      for (int t6 = 0; t6 < 6; t6++) {
        int g = gts[t6] * 16 + col16;
        int k8 = kk * 4 + quad;
        f16x8 b = *(const f16x8*)&WihL[g * 64 + ((k8 + g) & 7) * 8];
        #pragma unroll
        for (int mt = 0; mt < 2; mt++)
          acc[t6][mt] = __builtin_amdgcn_mfma_f32_16x16x32_f16(gah[kk][mt], b, acc[t6][mt], 0, 0, 0);
      }
    }

    #pragma unroll
    for (int mt = 0; mt < 2; mt++) {
      #pragma unroll
      for (int r = 0; r < 4; r++) {
        #pragma unroll
        for (int js = 0; js < 2; js++) {
          float R  = acc[0 + js][mt][r] + bR[js];
          float Z  = acc[2 + js][mt][r] + bZ[js];
          float Ni = acc[4 + js][mt][r] + bNi[js];
          float Nh = acc[6 + js][mt][r] + bNh[js];
          float rg = fast_sigmoid(R);
          float zg = fast_sigmoid(Z);
          float nn = fast_tanh(Ni + rg * Nh);
          float hn = nn + zg * (hreg[mt][r][js] - nn);
          hreg[mt][r][js] = hn;
          hnxt[waddr[mt][r][js]] = (_Float16)hn;
        }
      }
    }
    __syncthreads();
  }

  #pragma unroll
  for (int mt = 0; mt < 2; mt++) {
    #pragma unroll
    for (int r = 0; r < 4; r++) {
      float py = hreg[mt][r][0] * hw[0] + hreg[mt][r][1] * hw[1];
      py = quad_sum16(py);
      if (col16 == 0) yL[wave][mt * 16 + quad * 4 + r] = py;
    }
  }
  __syncthreads();
  if (tid < 32)
    out[m0 + tid] = yL[0][tid] + yL[1][tid] + yL[2][tid] + yL[3][tid] + headb[0];
}

extern "C" void kernel_launch(void* const* d_in, const int* in_sizes, int n_in,
                              void* d_out, int out_size, void* d_ws, size_t ws_size,
                              hipStream_t stream) {
  const float* x_seq = (const float*)d_in[0];
  const int*   edge  = (const int*)d_in[1];
  const float* Wl0   = (const float*)d_in[2];
  const float* Wr0   = (const float*)d_in[3];
  const float* b0    = (const float*)d_in[4];
  const float* g0    = (const float*)d_in[5];
  const float* be0   = (const float*)d_in[6];
  const float* Wl1   = (const float*)d_in[7];
  const float* Wr1   = (const float*)d_in[8];
  const float* b1    = (const float*)d_in[9];
  const float* g1    = (const float*)d_in[10];
  const float* be1   = (const float*)d_in[11];
  const float* Wih   = (const float*)d_in[12];
  const float* Whh   = (const float*)d_in[13];
  const float* bih   = (const float*)d_in[14];
  const float* bhh   = (const float*)d_in[15];
  const float* headW = (const float*)d_in[16];
  const float* headb = (const float*)d_in[17];
  float* out = (float*)d_out;

  const int* srcp = edge;
  const int* dstp = edge + NE;

  char* ws = (char*)d_ws;
  size_t off = 0;
  auto alloc = [&](size_t bytes) -> void* {
    void* p = ws + off;
    off += (bytes + 255) & ~(size_t)255;
    return p;
  };
  int*   cnt     = (int*)alloc(NN * 4);
  int*   row_ptr = (int*)alloc((NN + 1) * 4);
  int*   col     = (int*)alloc(NE * 4);
  float* deg_inv = (float*)alloc(NN * 4);
  float* xT      = (float*)alloc((size_t)NN * TS * 4);
  float* P       = (float*)alloc(512 * 4);
  _Float16* h0r  = (_Float16*)alloc((size_t)NN * 1024 * 2);        // 41 MB [n][16][64]
  _Float16* code2= (_Float16*)alloc((size_t)NN * 128 * 2);         // 5.12 MB dup'd LN codes
  _Float16* agg  = (_Float16*)alloc((size_t)NN * 1024 * 2);        // 41 MB [n][16][64]
  _Float16* Ht_all = (_Float16*)alloc((size_t)TS * NN * HG * 2);   // 41 MB [t][n][64]
  _Float16* WihF = (_Float16*)alloc((size_t)NG * HG * 2);
  _Float16* WhhF = (_Float16*)alloc((size_t)NG * HTT * 2);
  _Float16* Wchi = (_Float16*)alloc((size_t)HG * 128 * 2);
  _Float16* Wclo = (_Float16*)alloc((size_t)HG * 128 * 2);
  (void)ws_size; (void)in_sizes; (void)n_in; (void)out_size;

  k_setup<<<1250, 256, 0, stream>>>(x_seq, xT, Wih, WihF, Whh, WhhF,
                                    Wl1, Wr1, Wchi, Wclo,
                                    Wl0, Wr0, b0, g0, be0, P, cnt);
  k_hist<<<(NE + 255) / 256, 256, 0, stream>>>(dstp, cnt);
  k_scan<<<1, 1024, 0, stream>>>(cnt, row_ptr, deg_inv);
  k_fill<<<(NE + 255) / 256, 256, 0, stream>>>(srcp, dstp, cnt, col);
  k_h0_fused<<<NN / 4, 256, 0, stream>>>(xT, row_ptr, col, deg_inv, P, h0r, code2);
  k_gather<<<NN / 4, 256, 0, stream>>>(row_ptr, col, code2, P, agg);
  k_gemm<<<NN / 16, 256, 0, stream>>>(h0r, agg, Wchi, Wclo, b1, g1, be1, Ht_all);
  k_gru_all<<<NN / 32, 256, 0, stream>>>(Ht_all, WihF, WhhF, bih, bhh,
                                         headW, headb, out);
}